// Round 17
// baseline (1067.568 us; speedup 1.0000x reference)
//
#include <hip/hip_runtime.h>
#include <hip/hip_fp16.h>
#include <math.h>

// ws float offsets
#define OFF_TOKPROJ 0         // 12288 floats
#define OFF_ACC     12288     // 256 u64 = 512 floats (exact q30 prob sums)
#define OFF_SLOT2   12800     // 256*256 u32 (rare path, tagged q27 sums)
#define OFF_SLOTS   78336     // 256*1024 u32 (per-(t,row) q30 probs)
// total = 340,480 floats = 1.36 MB

#define THRESH30 (512ULL << 30)
#define THRESH27 (512ULL << 27)
#define SPIN_BOUND (1 << 18)

__device__ __forceinline__ float sigf(float x) {
    return __fdividef(1.f, 1.f + __expf(-x));
}
__device__ __forceinline__ float tanhf_fast(float x) {
    float e2 = __expf(-2.f * fabsf(x));
    float r = __fdividef(1.f - e2, 1.f + e2);
    return __uint_as_float(__float_as_uint(r) | (__float_as_uint(x) & 0x80000000u));
}
__device__ __forceinline__ unsigned int pack2(float x, float y) {
    union { unsigned int u; _Float16 h[2]; } v;
    v.h[0] = (_Float16)x; v.h[1] = (_Float16)y;
    return v.u;
}
__device__ __forceinline__ float dot2acc(unsigned int a, unsigned int b, float acc) {
#if __has_builtin(__builtin_amdgcn_fdot2)
    typedef _Float16 hf2 __attribute__((ext_vector_type(2)));
    union { unsigned int u; hf2 h; } ua, ub;
    ua.u = a; ub.u = b;
    return __builtin_amdgcn_fdot2(ua.h, ub.h, acc, false);
#else
    union { unsigned int u; _Float16 h[2]; } ua, ub;
    ua.u = a; ub.u = b;
    return acc + (float)ua.h[0] * (float)ub.h[0] + (float)ua.h[1] * (float)ub.h[1];
#endif
}

// ---------------- prep: tokproj table + zero SLOT2 ----------------
__global__ __launch_bounds__(64) void prep_k(
    const float* __restrict__ embed, const float* __restrict__ gwih,
    const float* __restrict__ gbih, float* __restrict__ ws)
{
    int blk = blockIdx.x, l = threadIdx.x;
    if (blk < 64) {
        float* tokproj = ws + OFF_TOKPROJ;
        int v = blk;
        for (int j = l; j < 192; j += 64) {
            float s = gbih[j];
            for (int d = 0; d < 64; ++d) s += embed[v * 64 + d] * gwih[j * 128 + d];
            tokproj[v * 192 + j] = s;
        }
    } else {
        float* z = ws + OFF_SLOT2;
        int base = (blk - 64) * 4096;
        for (int i = base + l; i < base + 4096; i += 64) z[i] = 0.f;
    }
}

// ------- fused: GRU producer wave + 3 trigger consumer waves per row -------
__global__ __launch_bounds__(256, 1) void fused_k(
    const int* __restrict__ seq, const float* __restrict__ gwhh,
    const float* __restrict__ gbhh, const float* __restrict__ lwih,
    const float* __restrict__ lwhh, const float* __restrict__ lbih,
    const float* __restrict__ lbhh, const float* __restrict__ tw,
    const float* __restrict__ tb, const float* __restrict__ hw,
    const float* __restrict__ hb, float* __restrict__ ws,
    float* __restrict__ out)
{
    int tid = threadIdx.x, w = tid >> 6, l = tid & 63;
    int r = blockIdx.x;
    int gw = r & 3;                       // GRU wave (rotates across SIMDs)
    const float* tokproj = ws + OFF_TOKPROJ;
    unsigned int* slots = (unsigned int*)(ws + OFF_SLOTS);

    __shared__ float hbuf[2][19][64];     // double-buffered h window
    __shared__ int toks[256];
    __shared__ unsigned int hs2w[4][16];  // per-wave packed LSTM hidden

    for (int i = tid; i < 256; i += 256) toks[i] = seq[r * 256 + i];

    if (w == gw) {
        // ================= GRU producer =================
        float wh0[64], wh1[64], wh2[64];
        #pragma unroll
        for (int d4 = 0; d4 < 16; ++d4) {
            float4 a0 = *(const float4*)(gwhh + (size_t)l * 64 + d4 * 4);
            float4 a1 = *(const float4*)(gwhh + (size_t)(64 + l) * 64 + d4 * 4);
            float4 a2 = *(const float4*)(gwhh + (size_t)(128 + l) * 64 + d4 * 4);
            wh0[d4*4] = a0.x; wh0[d4*4+1] = a0.y; wh0[d4*4+2] = a0.z; wh0[d4*4+3] = a0.w;
            wh1[d4*4] = a1.x; wh1[d4*4+1] = a1.y; wh1[d4*4+2] = a1.z; wh1[d4*4+3] = a1.w;
            wh2[d4*4] = a2.x; wh2[d4*4+1] = a2.y; wh2[d4*4+2] = a2.z; wh2[d4*4+3] = a2.w;
        }
        float g0b = gbhh[l], g1b = gbhh[64 + l], g2b = gbhh[128 + l];
        float h = 0.f;

        for (int c = 0; c < 16; ++c) {
            int cb = c & 1, pb = cb ^ 1;
            // boundary entries 0..2 = h_{c*16-3 .. c*16-1}
            #pragma unroll
            for (int j = 0; j < 3; ++j)
                hbuf[cb][j][l] = (c == 0) ? 0.f : hbuf[pb][16 + j][l];
            for (int s = 0; s < 16; ++s) {
                int t = c * 16 + s;
                int tok = toks[t];
                float gi0 = tokproj[tok * 192 + l], gi1 = tokproj[tok * 192 + 64 + l],
                      gi2 = tokproj[tok * 192 + 128 + l];
                float A0[4] = {0.f,0.f,0.f,0.f}, A1[4] = {0.f,0.f,0.f,0.f}, A2[4] = {0.f,0.f,0.f,0.f};
                #pragma unroll
                for (int d4 = 0; d4 < 16; ++d4) {
                    float4 hv = *(const float4*)&hbuf[cb][s + 2][d4 * 4];
                    A0[d4 & 3] += hv.x*wh0[d4*4] + hv.y*wh0[d4*4+1] + hv.z*wh0[d4*4+2] + hv.w*wh0[d4*4+3];
                    A1[d4 & 3] += hv.x*wh1[d4*4] + hv.y*wh1[d4*4+1] + hv.z*wh1[d4*4+2] + hv.w*wh1[d4*4+3];
                    A2[d4 & 3] += hv.x*wh2[d4*4] + hv.y*wh2[d4*4+1] + hv.z*wh2[d4*4+2] + hv.w*wh2[d4*4+3];
                }
                float gh0 = g0b + ((A0[0]+A0[1]) + (A0[2]+A0[3]));
                float gh1 = g1b + ((A1[0]+A1[1]) + (A1[2]+A1[3]));
                float gh2 = g2b + ((A2[0]+A2[1]) + (A2[2]+A2[3]));
                float r_ = sigf(gi0 + gh0), z_ = sigf(gi1 + gh1);
                float n_ = tanhf_fast(gi2 + r_ * gh2);
                h = (1.f - z_) * n_ + z_ * h;
                hbuf[cb][s + 3][l] = h;
            }
            __syncthreads();
        }
        // logits from h_255 (hbuf[1][18])
        float sL = hb[l];
        #pragma unroll
        for (int d4 = 0; d4 < 16; ++d4) {
            float4 w4 = *(const float4*)(hw + (size_t)l * 64 + d4 * 4);
            float4 hv = *(const float4*)&hbuf[1][18][d4 * 4];
            sL += hv.x * w4.x + hv.y * w4.y + hv.z * w4.z + hv.w * w4.w;
        }
        out[r * 64 + l] = sL;
    } else {
        // ================= trigger consumers =================
        int tr = (w - gw + 3) & 3;        // 0,1,2
        unsigned int wl0h[32], wl1h[32], lh0h[16], lh1h[16];
        #pragma unroll
        for (int d2 = 0; d2 < 32; ++d2) {
            wl0h[d2] = pack2(lwih[(size_t)l * 64 + 2*d2], lwih[(size_t)l * 64 + 2*d2 + 1]);
            wl1h[d2] = pack2(lwih[(size_t)(64 + l) * 64 + 2*d2], lwih[(size_t)(64 + l) * 64 + 2*d2 + 1]);
        }
        #pragma unroll
        for (int d2 = 0; d2 < 16; ++d2) {
            lh0h[d2] = pack2(lwhh[(size_t)l * 32 + 2*d2], lwhh[(size_t)l * 32 + 2*d2 + 1]);
            lh1h[d2] = pack2(lwhh[(size_t)(64 + l) * 32 + 2*d2], lwhh[(size_t)(64 + l) * 32 + 2*d2 + 1]);
        }
        float lb0 = lbih[l] + lbhh[l], lb1 = lbih[64 + l] + lbhh[64 + l];
        float twr = (l < 32) ? tw[l] : 0.f;
        float tb0 = tb[0];

        // process triggers of chunk cc from buffer bb
        auto do_chunk = [&](int cc) {
            int bb = cc & 1;
            int base = cc * 16;
            int tlo = (cc == 0) ? 3 : base;
            int n = base + 16 - tlo;
            int ta = tlo + (tr * n) / 3;
            int tb_ = tlo + ((tr + 1) * n) / 3;
            // proj for window tt (buffer idx tt - base + 3)
            auto proj = [&](int tt, float& p0, float& p1) {
                int idx = tt - base + 3;
                p0 = lb0; p1 = lb1;
                #pragma unroll
                for (int d4 = 0; d4 < 16; ++d4) {
                    float4 hv = *(const float4*)&hbuf[bb][idx][d4 * 4];
                    unsigned int a = pack2(hv.x, hv.y), b2 = pack2(hv.z, hv.w);
                    p0 = dot2acc(a, wl0h[2*d4], p0); p0 = dot2acc(b2, wl0h[2*d4+1], p0);
                    p1 = dot2acc(a, wl1h[2*d4], p1); p1 = dot2acc(b2, wl1h[2*d4+1], p1);
                }
            };
            float P00, P01, P02, P03, P10, P11, P12, P13;
            for (int t = ta; t < tb_; ++t) {
                if (t == ta) {
                    proj(t - 3, P00, P10); proj(t - 2, P01, P11);
                    proj(t - 1, P02, P12); proj(t,     P03, P13);
                } else {
                    P00 = P01; P10 = P11; P01 = P02; P11 = P12;
                    P02 = P03; P12 = P13; proj(t, P03, P13);
                }
                float hh = 0.f, cc2 = 0.f;
                #pragma unroll
                for (int k = 0; k < 4; ++k) {
                    float q0 = (k == 0) ? P00 : (k == 1) ? P01 : (k == 2) ? P02 : P03;
                    float q1 = (k == 0) ? P10 : (k == 1) ? P11 : (k == 2) ? P12 : P13;
                    if (k) {
                        #pragma unroll
                        for (int d4 = 0; d4 < 4; ++d4) {
                            uint4 ha = *(const uint4*)&hs2w[w][d4 * 4];
                            q0 = dot2acc(ha.x, lh0h[d4*4+0], q0); q1 = dot2acc(ha.x, lh1h[d4*4+0], q1);
                            q0 = dot2acc(ha.y, lh0h[d4*4+1], q0); q1 = dot2acc(ha.y, lh1h[d4*4+1], q1);
                            q0 = dot2acc(ha.z, lh0h[d4*4+2], q0); q1 = dot2acc(ha.z, lh1h[d4*4+2], q1);
                            q0 = dot2acc(ha.w, lh0h[d4*4+3], q0); q1 = dot2acc(ha.w, lh1h[d4*4+3], q1);
                        }
                    }
                    float s0 = sigf(q0);              // lanes<32: i, >=32: f
                    float t1 = tanhf_fast(q1);        // lanes<32: g
                    float s1 = sigf(q1);              // lanes>=32: o
                    float ff = __shfl(s0, l + 32);
                    float oo = __shfl(s1, l + 32);
                    float ncc = ff * cc2 + s0 * t1;
                    float nh = oo * tanhf_fast(ncc);
                    if (l < 32) { cc2 = ncc; hh = nh; }
                    if (k < 3) {
                        float a0 = __shfl(nh, 2 * l), a1 = __shfl(nh, 2 * l + 1);
                        if (l < 16) hs2w[w][l] = pack2(a0, a1);
                    }
                }
                float pp = (l < 32) ? hh * twr : 0.f;
                #pragma unroll
                for (int o = 32; o; o >>= 1) pp += __shfl_xor(pp, o);
                if (l == 0) {
                    float prob = sigf(pp + tb0);
                    unsigned long long q = (unsigned long long)llrint((double)prob * 1073741824.0);
                    if (q > 0x3FFFFFFFull) q = 0x3FFFFFFFull;
                    slots[(size_t)t * 1024 + r] = (unsigned int)q;
                }
            }
        };

        for (int c = 0; c < 16; ++c) {
            if (c > 0) do_chunk(c - 1);
            __syncthreads();
        }
        do_chunk(15);
    }
}

// ---------------- red: exact per-t reduction of 1024 row probs ----------
__global__ __launch_bounds__(256) void red_k(float* __restrict__ ws)
{
    int tid = threadIdx.x, w = tid >> 6, l = tid & 63;
    int t = 3 + blockIdx.x * 4 + w;
    if (t > 255) return;
    const unsigned int* slots = (const unsigned int*)(ws + OFF_SLOTS);
    unsigned long long* acc = (unsigned long long*)(ws + OFF_ACC);
    unsigned long long s = 0;
    #pragma unroll
    for (int k = 0; k < 16; ++k) s += slots[(size_t)t * 1024 + k * 64 + l];
    #pragma unroll
    for (int o = 32; o; o >>= 1) s += __shfl_xor(s, o);
    if (l == 0) acc[t] = s;
}

// ---------------- fin: inline verdict; no-op on no-fire; replay on fire ----
__global__ __launch_bounds__(256, 1) void fin_k(
    const int* __restrict__ seq, const float* __restrict__ memory,
    const float* __restrict__ gwih, const float* __restrict__ gwhh,
    const float* __restrict__ gbhh, const float* __restrict__ qw,
    const float* __restrict__ qb, const float* __restrict__ kw,
    const float* __restrict__ vw, const float* __restrict__ vb,
    const float* __restrict__ lwih, const float* __restrict__ lwhh,
    const float* __restrict__ lbih, const float* __restrict__ lbhh,
    const float* __restrict__ tw, const float* __restrict__ tb,
    const float* __restrict__ hw, const float* __restrict__ hb,
    float* __restrict__ ws, float* __restrict__ out)
{
    int tid = threadIdx.x, w = tid >> 6, l = tid & 63, b = blockIdx.x;
    const unsigned long long* acc = (const unsigned long long*)(ws + OFF_ACC);

    __shared__ int redmin[4];
    {
        int mymin = 1 << 30;
        if (tid >= 3 && acc[tid] > THRESH30) mymin = tid;
        #pragma unroll
        for (int o = 32; o; o >>= 1) mymin = min(mymin, __shfl_xor(mymin, o));
        if (l == 0) redmin[w] = mymin;
    }
    __syncthreads();
    int tc = min(min(redmin[0], redmin[1]), min(redmin[2], redmin[3]));
    if (tc > 255) {
        if (b == 0 && tid == 0) out[65536] = 0.f;
        return;                         // common path
    }

    int r = b * 4 + w;
    const float* tokproj = ws + OFF_TOKPROJ;
    unsigned int* S2 = (unsigned int*)(ws + OFF_SLOT2);

    __shared__ float hs[4][64], qs[4][64], us[4][64], rs[4][64];
    __shared__ float hs2f[4][32];
    __shared__ float PXl[4][4][128];
    __shared__ unsigned int probq[4];
    __shared__ int flagLds;
    __shared__ int toks[4][256];

    for (int k = 0; k < 4; ++k) toks[w][k * 64 + l] = seq[r * 256 + k * 64 + l];
    if (tid == 0) flagLds = 0;

    float wh0[64], wh1[64], wh2[64], wl0[64], wl1[64], lh0[32], lh1[32];
    #pragma unroll
    for (int d4 = 0; d4 < 16; ++d4) {
        float4 a0 = *(const float4*)(gwhh + (size_t)l * 64 + d4 * 4);
        float4 a1 = *(const float4*)(gwhh + (size_t)(64 + l) * 64 + d4 * 4);
        float4 a2 = *(const float4*)(gwhh + (size_t)(128 + l) * 64 + d4 * 4);
        float4 b0 = *(const float4*)(lwih + (size_t)l * 64 + d4 * 4);
        float4 b1 = *(const float4*)(lwih + (size_t)(64 + l) * 64 + d4 * 4);
        wh0[d4*4] = a0.x; wh0[d4*4+1] = a0.y; wh0[d4*4+2] = a0.z; wh0[d4*4+3] = a0.w;
        wh1[d4*4] = a1.x; wh1[d4*4+1] = a1.y; wh1[d4*4+2] = a1.z; wh1[d4*4+3] = a1.w;
        wh2[d4*4] = a2.x; wh2[d4*4+1] = a2.y; wh2[d4*4+2] = a2.z; wh2[d4*4+3] = a2.w;
        wl0[d4*4] = b0.x; wl0[d4*4+1] = b0.y; wl0[d4*4+2] = b0.z; wl0[d4*4+3] = b0.w;
        wl1[d4*4] = b1.x; wl1[d4*4+1] = b1.y; wl1[d4*4+2] = b1.z; wl1[d4*4+3] = b1.w;
    }
    #pragma unroll
    for (int d4 = 0; d4 < 8; ++d4) {
        float4 c0 = *(const float4*)(lwhh + (size_t)l * 32 + d4 * 4);
        float4 c1 = *(const float4*)(lwhh + (size_t)(64 + l) * 32 + d4 * 4);
        lh0[d4*4] = c0.x; lh0[d4*4+1] = c0.y; lh0[d4*4+2] = c0.z; lh0[d4*4+3] = c0.w;
        lh1[d4*4] = c1.x; lh1[d4*4+1] = c1.y; lh1[d4*4+2] = c1.z; lh1[d4*4+3] = c1.w;
    }
    float g0b = gbhh[l], g1b = gbhh[64 + l], g2b = gbhh[128 + l];
    float lb0 = lbih[l] + lbhh[l], lb1 = lbih[64 + l] + lbhh[64 + l];
    float twr = (l < 32) ? tw[l] : 0.f;
    float tb0 = tb[0];
    const float* mrow = memory + (size_t)r * 16384;

    float h = 0.f;
    hs[w][l] = 0.f;
    bool fire = false, brk = false;
    int cnt = 1;
    __syncthreads();

    for (int t = 0; t < 256; ++t) {
        int tok = toks[w][t];
        float gi0 = tokproj[tok * 192 + l], gi1 = tokproj[tok * 192 + 64 + l],
              gi2 = tokproj[tok * 192 + 128 + l];
        float gh0 = g0b, gh1 = g1b, gh2 = g2b;
        #pragma unroll
        for (int d4 = 0; d4 < 16; ++d4) {
            float4 hv = *(const float4*)&hs[w][d4 * 4];
            gh0 += hv.x*wh0[d4*4] + hv.y*wh0[d4*4+1] + hv.z*wh0[d4*4+2] + hv.w*wh0[d4*4+3];
            gh1 += hv.x*wh1[d4*4] + hv.y*wh1[d4*4+1] + hv.z*wh1[d4*4+2] + hv.w*wh1[d4*4+3];
            gh2 += hv.x*wh2[d4*4] + hv.y*wh2[d4*4+1] + hv.z*wh2[d4*4+2] + hv.w*wh2[d4*4+3];
        }
        if (fire) {
            float q = qb[l];
            #pragma unroll
            for (int d4 = 0; d4 < 16; ++d4) {
                float4 q4 = *(const float4*)(qw + (size_t)l * 64 + d4 * 4);
                float4 hv = *(const float4*)&hs[w][d4 * 4];
                q += hv.x * q4.x + hv.y * q4.y + hv.z * q4.z + hv.w * q4.w;
            }
            qs[w][l] = q;
            float qk = 0.f;
            for (int e = 0; e < 64; ++e) qk += qs[w][e] * kw[(size_t)e * 64 + l];
            qk *= 0.125f;
            us[w][l] = qk;
            float sc[4];
            for (int k = 0; k < 4; ++k) {
                const float* mp = mrow + (size_t)(k * 64 + l) * 64;
                float s = 0.f;
                #pragma unroll
                for (int d4 = 0; d4 < 16; ++d4) {
                    float4 m4 = *(const float4*)(mp + d4 * 4);
                    float4 kv = *(const float4*)&us[w][d4 * 4];
                    s += m4.x * kv.x + m4.y * kv.y + m4.z * kv.z + m4.w * kv.w;
                }
                sc[k] = s;
            }
            float mx = fmaxf(fmaxf(sc[0], sc[1]), fmaxf(sc[2], sc[3]));
            for (int o = 32; o; o >>= 1) mx = fmaxf(mx, __shfl_xor(mx, o));
            float den = 0.f;
            #pragma unroll
            for (int k = 0; k < 4; ++k) { sc[k] = expf(sc[k] - mx); den += sc[k]; }
            for (int o = 32; o; o >>= 1) den += __shfl_xor(den, o);
            float u = 0.f;
            for (int m = 0; m < 256; ++m) {
                float wm = __shfl(sc[m >> 6], m & 63);
                u += wm * mrow[(size_t)m * 64 + l];
            }
            u /= den;
            us[w][l] = u;
            float ret = vb[l];
            #pragma unroll
            for (int d4 = 0; d4 < 16; ++d4) {
                float4 v4 = *(const float4*)(vw + (size_t)l * 64 + d4 * 4);
                float4 uv = *(const float4*)&us[w][d4 * 4];
                ret += uv.x * v4.x + uv.y * v4.y + uv.z * v4.z + uv.w * v4.w;
            }
            rs[w][l] = ret;
            for (int e = 0; e < 64; ++e) {
                float re = rs[w][e];
                gi0 += re * gwih[(size_t)l * 128 + 64 + e];
                gi1 += re * gwih[(size_t)(64 + l) * 128 + 64 + e];
                gi2 += re * gwih[(size_t)(128 + l) * 128 + 64 + e];
            }
        }
        fire = false;
        float r_ = sigf(gi0 + gh0), z_ = sigf(gi1 + gh1);
        float n_ = tanhf_fast(gi2 + r_ * gh2);
        h = (1.f - z_) * n_ + z_ * h;
        hs[w][l] = h;

        float p0 = lb0, p1 = lb1;
        #pragma unroll
        for (int d4 = 0; d4 < 16; ++d4) {
            float4 hv = *(const float4*)&hs[w][d4 * 4];
            p0 += hv.x*wl0[d4*4] + hv.y*wl0[d4*4+1] + hv.z*wl0[d4*4+2] + hv.w*wl0[d4*4+3];
            p1 += hv.x*wl1[d4*4] + hv.y*wl1[d4*4+1] + hv.z*wl1[d4*4+2] + hv.w*wl1[d4*4+3];
        }
        PXl[w][t & 3][l] = p0; PXl[w][t & 3][64 + l] = p1;

        if (t == tc) {
            fire = true;
        } else if (t > tc) {
            float hh = 0.f, cc = 0.f;
            #pragma unroll
            for (int k = 0; k < 4; ++k) {
                int s2 = (t - 3 + k) & 3;
                float q0 = PXl[w][s2][l], q1 = PXl[w][s2][64 + l];
                if (k) {
                    #pragma unroll
                    for (int d4 = 0; d4 < 8; ++d4) {
                        float4 hv = *(const float4*)&hs2f[w][d4 * 4];
                        q0 += hv.x*lh0[d4*4] + hv.y*lh0[d4*4+1] + hv.z*lh0[d4*4+2] + hv.w*lh0[d4*4+3];
                        q1 += hv.x*lh1[d4*4] + hv.y*lh1[d4*4+1] + hv.z*lh1[d4*4+2] + hv.w*lh1[d4*4+3];
                    }
                }
                float f_ = __shfl(q0, l + 32), o_ = __shfl(q1, l + 32);
                float ig = sigf(q0), ff = sigf(f_), gg = tanhf_fast(q1), oo = sigf(o_);
                float ncc = ff * cc + ig * gg;
                float nhh = oo * tanhf_fast(ncc);
                if (l < 32) { cc = ncc; hh = nhh; hs2f[w][l] = nhh; }
            }
            float pp = (l < 32) ? hh * twr : 0.f;
            #pragma unroll
            for (int o = 32; o; o >>= 1) pp += __shfl_xor(pp, o);
            if (l == 0) {
                float prob = sigf(pp + tb0);
                unsigned long long q = (unsigned long long)llrint((double)prob * 134217728.0);
                if (q > 0x7FFFFFFull) q = 0x7FFFFFFull;
                probq[w] = (unsigned int)q;
            }
            __syncthreads();
            if (w == 0 && l == 0) {
                unsigned int s = probq[0] + probq[1] + probq[2] + probq[3];
                __hip_atomic_store(&S2[(size_t)t * 256 + b], (1u << 30) | s,
                                   __ATOMIC_RELAXED, __HIP_MEMORY_SCOPE_AGENT);
            }
            if (w == 0) {
                unsigned long long tot = 0; int spin = 0; bool ok = true;
                if (!brk) {
                    for (;;) {
                        bool all4 = true; tot = 0;
                        #pragma unroll
                        for (int k2 = 0; k2 < 4; ++k2) {
                            unsigned int v = __hip_atomic_load(&S2[(size_t)t * 256 + k2 * 64 + l],
                                                               __ATOMIC_RELAXED, __HIP_MEMORY_SCOPE_AGENT);
                            all4 &= ((v >> 30) == 1u);
                            tot += (v & 0x3FFFFFFFu);
                        }
                        if (__all(all4)) break;
                        if (++spin > SPIN_BOUND) { ok = false; brk = true; break; }
                        __builtin_amdgcn_s_sleep(1);
                    }
                } else ok = false;
                #pragma unroll
                for (int o = 32; o; o >>= 1) tot += __shfl_xor(tot, o);
                int dec = (ok && tot > THRESH27) ? 1 : 0;
                cnt += dec;
                if (l == 0) flagLds = dec;
            }
            __syncthreads();
            fire = (flagLds != 0);
        }
    }

    float sL = hb[l];
    #pragma unroll
    for (int d4 = 0; d4 < 16; ++d4) {
        float4 w4 = *(const float4*)(hw + (size_t)l * 64 + d4 * 4);
        float4 hv = *(const float4*)&hs[w][d4 * 4];
        sL += hv.x * w4.x + hv.y * w4.y + hv.z * w4.z + hv.w * w4.w;
    }
    out[r * 64 + l] = sL;
    if (b == 0 && w == 0 && l == 0)
        out[65536] = brk ? -1234.f : (float)cnt / 256.f;
}

extern "C" void kernel_launch(void* const* d_in, const int* in_sizes, int n_in,
                              void* d_out, int out_size, void* d_ws, size_t ws_size,
                              hipStream_t stream)
{
    const int*   seq    = (const int*)d_in[0];
    const float* memory = (const float*)d_in[1];
    const float* embed  = (const float*)d_in[2];
    const float* gwih   = (const float*)d_in[3];
    const float* gwhh   = (const float*)d_in[4];
    const float* gbih   = (const float*)d_in[5];
    const float* gbhh   = (const float*)d_in[6];
    const float* qw     = (const float*)d_in[7];
    const float* qb     = (const float*)d_in[8];
    const float* kw     = (const float*)d_in[9];
    // d_in[10] = k_b : cancels in softmax, unused
    const float* vw     = (const float*)d_in[11];
    const float* vb     = (const float*)d_in[12];
    const float* lwih   = (const float*)d_in[13];
    const float* lwhh   = (const float*)d_in[14];
    const float* lbih   = (const float*)d_in[15];
    const float* lbhh   = (const float*)d_in[16];
    const float* tw     = (const float*)d_in[17];
    const float* tb     = (const float*)d_in[18];
    const float* hw     = (const float*)d_in[19];
    const float* hb     = (const float*)d_in[20];
    float* ws = (float*)d_ws;
    float* out = (float*)d_out;

    prep_k<<<80, 64, 0, stream>>>(embed, gwih, gbih, ws);
    fused_k<<<1024, 256, 0, stream>>>(seq, gwhh, gbhh, lwih, lwhh, lbih, lbhh,
                                      tw, tb, hw, hb, ws, out);
    red_k<<<64, 256, 0, stream>>>(ws);
    fin_k<<<256, 256, 0, stream>>>(seq, memory, gwih, gwhh, gbhh, qw, qb, kw,
                                   vw, vb, lwih, lwhh, lbih, lbhh, tw, tb,
                                   hw, hb, ws, out);
}

// Round 18
// 509.252 us; speedup vs baseline: 2.0963x; 2.0963x over previous
//
#include <hip/hip_runtime.h>
#include <hip/hip_fp16.h>
#include <math.h>

// ws float offsets
#define OFF_TOKPROJ 0         // 12288 floats
#define OFF_ACC     12288     // 256 u64 = 512 floats
#define OFF_SLOT2   12800     // 256*256 u32 (rare path)
#define OFF_SLOTS   78336     // 256*1024 u32 (per-(t,row) q30 probs)

#define THRESH30 (512ULL << 30)
#define THRESH27 (512ULL << 27)
#define SPIN_BOUND (1 << 18)

__device__ __forceinline__ float sigf(float x) {
    return __fdividef(1.f, 1.f + __expf(-x));
}
__device__ __forceinline__ float tanhf_fast(float x) {
    float e2 = __expf(-2.f * fabsf(x));
    float r = __fdividef(1.f - e2, 1.f + e2);
    return __uint_as_float(__float_as_uint(r) | (__float_as_uint(x) & 0x80000000u));
}
__device__ __forceinline__ unsigned int pack2(float x, float y) {
    union { unsigned int u; _Float16 h[2]; } v;
    v.h[0] = (_Float16)x; v.h[1] = (_Float16)y;
    return v.u;
}
__device__ __forceinline__ float unplo(unsigned int u) {
    union { unsigned int x; _Float16 h[2]; } v; v.x = u; return (float)v.h[0];
}
__device__ __forceinline__ float unphi(unsigned int u) {
    union { unsigned int x; _Float16 h[2]; } v; v.x = u; return (float)v.h[1];
}
__device__ __forceinline__ float dot2acc(unsigned int a, unsigned int b, float acc) {
#if __has_builtin(__builtin_amdgcn_fdot2)
    typedef _Float16 hf2 __attribute__((ext_vector_type(2)));
    union { unsigned int u; hf2 h; } ua, ub;
    ua.u = a; ub.u = b;
    return __builtin_amdgcn_fdot2(ua.h, ub.h, acc, false);
#else
    union { unsigned int u; _Float16 h[2]; } ua, ub;
    ua.u = a; ub.u = b;
    return acc + (float)ua.h[0] * (float)ub.h[0] + (float)ua.h[1] * (float)ub.h[1];
#endif
}

// ---------------- prep: tokproj table + zero SLOT2 ----------------
__global__ __launch_bounds__(64) void prep_k(
    const float* __restrict__ embed, const float* __restrict__ gwih,
    const float* __restrict__ gbih, float* __restrict__ ws)
{
    int blk = blockIdx.x, l = threadIdx.x;
    if (blk < 64) {
        float* tokproj = ws + OFF_TOKPROJ;
        int v = blk;
        for (int j = l; j < 192; j += 64) {
            float s = gbih[j];
            for (int d = 0; d < 64; ++d) s += embed[v * 64 + d] * gwih[j * 128 + d];
            tokproj[v * 192 + j] = s;
        }
    } else {
        float* z = ws + OFF_SLOT2;
        int base = (blk - 64) * 4096;
        for (int i = base + l; i < base + 4096; i += 64) z[i] = 0.f;
    }
}

// --- fused: 4 GRU producer waves + 4 trigger consumer waves per block ------
__global__ __launch_bounds__(512) void fused_k(
    const int* __restrict__ seq, const float* __restrict__ gwhh,
    const float* __restrict__ gbhh, const float* __restrict__ lwih,
    const float* __restrict__ lwhh, const float* __restrict__ lbih,
    const float* __restrict__ lbhh, const float* __restrict__ tw,
    const float* __restrict__ tb, const float* __restrict__ hw,
    const float* __restrict__ hb, float* __restrict__ ws,
    float* __restrict__ out)
{
    int tid = threadIdx.x, w = tid >> 6, l = tid & 63, b = blockIdx.x;
    const float* tokproj = ws + OFF_TOKPROJ;
    unsigned int* slots = (unsigned int*)(ws + OFF_SLOTS);

    __shared__ unsigned int hbuf[4][2][19][32];   // packed fp16 h window / row
    __shared__ unsigned int pwinp[4][19][64];     // packed (p0,p1) projections
    __shared__ unsigned int hs2p[4][2][16];       // packed LSTM hidden (A,B)
    __shared__ int toks[4][256];

    for (int i = tid; i < 1024; i += 512) toks[i >> 8][i & 255] = seq[(size_t)b * 1024 + i];
    __syncthreads();

    if (w < 4) {
        // ================= GRU producer (row r) =================
        int r = b * 4 + w;
        unsigned int wh0h[32], wh1h[32], wh2h[32];
        #pragma unroll
        for (int d2 = 0; d2 < 32; ++d2) {
            wh0h[d2] = pack2(gwhh[(size_t)l * 64 + 2*d2], gwhh[(size_t)l * 64 + 2*d2 + 1]);
            wh1h[d2] = pack2(gwhh[(size_t)(64 + l) * 64 + 2*d2], gwhh[(size_t)(64 + l) * 64 + 2*d2 + 1]);
            wh2h[d2] = pack2(gwhh[(size_t)(128 + l) * 64 + 2*d2], gwhh[(size_t)(128 + l) * 64 + 2*d2 + 1]);
        }
        float g0b = gbhh[l], g1b = gbhh[64 + l], g2b = gbhh[128 + l];
        float h = 0.f;
        if (l < 32) { hbuf[w][0][0][l] = 0u; hbuf[w][0][1][l] = 0u; hbuf[w][0][2][l] = 0u; }
        int tok0 = toks[w][0];
        float gi0 = tokproj[tok0 * 192 + l], gi1 = tokproj[tok0 * 192 + 64 + l],
              gi2 = tokproj[tok0 * 192 + 128 + l];

        for (int c = 0; c < 16; ++c) {
            int cb = c & 1;
            if (c > 0 && l < 32) {
                hbuf[w][cb][0][l] = hbuf[w][cb ^ 1][16][l];
                hbuf[w][cb][1][l] = hbuf[w][cb ^ 1][17][l];
                hbuf[w][cb][2][l] = hbuf[w][cb ^ 1][18][l];
            }
            for (int s = 0; s < 16; ++s) {
                int t = c * 16 + s;
                float ni0 = 0.f, ni1 = 0.f, ni2 = 0.f;
                if (t < 255) {
                    int tk = toks[w][t + 1];
                    ni0 = tokproj[tk * 192 + l];
                    ni1 = tokproj[tk * 192 + 64 + l];
                    ni2 = tokproj[tk * 192 + 128 + l];
                }
                float A00 = 0.f, A01 = 0.f, A10 = 0.f, A11 = 0.f, A20 = 0.f, A21 = 0.f;
                #pragma unroll
                for (int d8 = 0; d8 < 8; ++d8) {
                    uint4 hv = *(const uint4*)&hbuf[w][cb][s + 2][d8 * 4];
                    A00 = dot2acc(hv.x, wh0h[d8*4+0], A00); A01 = dot2acc(hv.y, wh0h[d8*4+1], A01);
                    A00 = dot2acc(hv.z, wh0h[d8*4+2], A00); A01 = dot2acc(hv.w, wh0h[d8*4+3], A01);
                    A10 = dot2acc(hv.x, wh1h[d8*4+0], A10); A11 = dot2acc(hv.y, wh1h[d8*4+1], A11);
                    A10 = dot2acc(hv.z, wh1h[d8*4+2], A10); A11 = dot2acc(hv.w, wh1h[d8*4+3], A11);
                    A20 = dot2acc(hv.x, wh2h[d8*4+0], A20); A21 = dot2acc(hv.y, wh2h[d8*4+1], A21);
                    A20 = dot2acc(hv.z, wh2h[d8*4+2], A20); A21 = dot2acc(hv.w, wh2h[d8*4+3], A21);
                }
                float gh0 = g0b + A00 + A01;
                float gh1 = g1b + A10 + A11;
                float gh2 = g2b + A20 + A21;
                float r_ = sigf(gi0 + gh0), z_ = sigf(gi1 + gh1);
                float n_ = tanhf_fast(gi2 + r_ * gh2);
                h = (1.f - z_) * n_ + z_ * h;
                float a0 = __shfl(h, 2 * l), a1 = __shfl(h, 2 * l + 1);
                if (l < 32) hbuf[w][cb][s + 3][l] = pack2(a0, a1);
                gi0 = ni0; gi1 = ni1; gi2 = ni2;
            }
            __syncthreads();
        }
        // logits from h_255 (hbuf[w][1][18], packed)
        float sL = hb[l];
        #pragma unroll
        for (int d4 = 0; d4 < 16; ++d4) {
            float4 w4 = *(const float4*)(hw + (size_t)l * 64 + d4 * 4);
            unsigned int h0 = hbuf[w][1][18][d4 * 2], h1 = hbuf[w][1][18][d4 * 2 + 1];
            sL += unplo(h0) * w4.x + unphi(h0) * w4.y + unplo(h1) * w4.z + unphi(h1) * w4.w;
        }
        out[r * 64 + l] = sL;
    } else {
        // ================= trigger consumer (row rw) =================
        int rw = w - 4;
        int r = b * 4 + rw;
        unsigned int wl0h[32], wl1h[32], lh0h[16], lh1h[16];
        #pragma unroll
        for (int d2 = 0; d2 < 32; ++d2) {
            wl0h[d2] = pack2(lwih[(size_t)l * 64 + 2*d2], lwih[(size_t)l * 64 + 2*d2 + 1]);
            wl1h[d2] = pack2(lwih[(size_t)(64 + l) * 64 + 2*d2], lwih[(size_t)(64 + l) * 64 + 2*d2 + 1]);
        }
        #pragma unroll
        for (int d2 = 0; d2 < 16; ++d2) {
            lh0h[d2] = pack2(lwhh[(size_t)l * 32 + 2*d2], lwhh[(size_t)l * 32 + 2*d2 + 1]);
            lh1h[d2] = pack2(lwhh[(size_t)(64 + l) * 32 + 2*d2], lwhh[(size_t)(64 + l) * 32 + 2*d2 + 1]);
        }
        float lb0 = lbih[l] + lbhh[l], lb1 = lbih[64 + l] + lbhh[64 + l];
        float twr = (l < 32) ? tw[l] : 0.f;
        float tb0 = tb[0];

        auto do_chunk = [&](int cc) {
            int bb = cc & 1, base = cc * 16;
            // phase 1: 19 projections from packed h window
            for (int i = 0; i < 19; ++i) {
                float p0 = lb0, p1 = lb1;
                #pragma unroll
                for (int d8 = 0; d8 < 8; ++d8) {
                    uint4 hv = *(const uint4*)&hbuf[rw][bb][i][d8 * 4];
                    p0 = dot2acc(hv.x, wl0h[d8*4+0], p0); p1 = dot2acc(hv.x, wl1h[d8*4+0], p1);
                    p0 = dot2acc(hv.y, wl0h[d8*4+1], p0); p1 = dot2acc(hv.y, wl1h[d8*4+1], p1);
                    p0 = dot2acc(hv.z, wl0h[d8*4+2], p0); p1 = dot2acc(hv.z, wl1h[d8*4+2], p1);
                    p0 = dot2acc(hv.w, wl0h[d8*4+3], p0); p1 = dot2acc(hv.w, wl1h[d8*4+3], p1);
                }
                pwinp[rw][i][l] = pack2(p0, p1);
            }
            // phase 2: 16 triggers, 2-chain ILP (j, j+8)
            for (int jp = 0; jp < 8; ++jp) {
                int ja = jp, jb2 = jp + 8;
                bool hasA = (base + ja >= 3);
                float hhA = 0.f, ccA = 0.f, hhB = 0.f, ccB = 0.f;
                #pragma unroll
                for (int k = 0; k < 4; ++k) {
                    unsigned int uA = pwinp[rw][ja + k][l];
                    float q0A = unplo(uA), q1A = unphi(uA);
                    unsigned int uB = pwinp[rw][jb2 + k][l];
                    float q0B = unplo(uB), q1B = unphi(uB);
                    if (k) {
                        #pragma unroll
                        for (int d4 = 0; d4 < 4; ++d4) {
                            uint4 ha = *(const uint4*)&hs2p[rw][0][d4 * 4];
                            q0A = dot2acc(ha.x, lh0h[d4*4+0], q0A); q1A = dot2acc(ha.x, lh1h[d4*4+0], q1A);
                            q0A = dot2acc(ha.y, lh0h[d4*4+1], q0A); q1A = dot2acc(ha.y, lh1h[d4*4+1], q1A);
                            q0A = dot2acc(ha.z, lh0h[d4*4+2], q0A); q1A = dot2acc(ha.z, lh1h[d4*4+2], q1A);
                            q0A = dot2acc(ha.w, lh0h[d4*4+3], q0A); q1A = dot2acc(ha.w, lh1h[d4*4+3], q1A);
                        }
                        #pragma unroll
                        for (int d4 = 0; d4 < 4; ++d4) {
                            uint4 hb2 = *(const uint4*)&hs2p[rw][1][d4 * 4];
                            q0B = dot2acc(hb2.x, lh0h[d4*4+0], q0B); q1B = dot2acc(hb2.x, lh1h[d4*4+0], q1B);
                            q0B = dot2acc(hb2.y, lh0h[d4*4+1], q0B); q1B = dot2acc(hb2.y, lh1h[d4*4+1], q1B);
                            q0B = dot2acc(hb2.z, lh0h[d4*4+2], q0B); q1B = dot2acc(hb2.z, lh1h[d4*4+2], q1B);
                            q0B = dot2acc(hb2.w, lh0h[d4*4+3], q0B); q1B = dot2acc(hb2.w, lh1h[d4*4+3], q1B);
                        }
                    }
                    float s0A = sigf(q0A);
                    float t1A = tanhf_fast(q1A);
                    float s1A = sigf(q1A);
                    float ffA = __shfl(s0A, l + 32);
                    float ooA = __shfl(s1A, l + 32);
                    float nccA = ffA * ccA + s0A * t1A;
                    float nhA = ooA * tanhf_fast(nccA);
                    if (l < 32) { ccA = nccA; hhA = nhA; }
                    float s0B = sigf(q0B);
                    float t1B = tanhf_fast(q1B);
                    float s1B = sigf(q1B);
                    float ffB = __shfl(s0B, l + 32);
                    float ooB = __shfl(s1B, l + 32);
                    float nccB = ffB * ccB + s0B * t1B;
                    float nhB = ooB * tanhf_fast(nccB);
                    if (l < 32) { ccB = nccB; hhB = nhB; }
                    if (k < 3) {
                        float a0 = __shfl(nhA, 2 * l), a1 = __shfl(nhA, 2 * l + 1);
                        if (l < 16) hs2p[rw][0][l] = pack2(a0, a1);
                        float b0 = __shfl(nhB, 2 * l), b1 = __shfl(nhB, 2 * l + 1);
                        if (l < 16) hs2p[rw][1][l] = pack2(b0, b1);
                    }
                }
                float ppA = (l < 32) ? hhA * twr : 0.f;
                #pragma unroll
                for (int o = 32; o; o >>= 1) ppA += __shfl_xor(ppA, o);
                if (hasA && l == 0) {
                    float prob = sigf(ppA + tb0);
                    unsigned long long q = (unsigned long long)llrint((double)prob * 1073741824.0);
                    if (q > 0x3FFFFFFFull) q = 0x3FFFFFFFull;
                    slots[(size_t)(base + ja) * 1024 + r] = (unsigned int)q;
                }
                float ppB = (l < 32) ? hhB * twr : 0.f;
                #pragma unroll
                for (int o = 32; o; o >>= 1) ppB += __shfl_xor(ppB, o);
                if (l == 0) {
                    float prob = sigf(ppB + tb0);
                    unsigned long long q = (unsigned long long)llrint((double)prob * 1073741824.0);
                    if (q > 0x3FFFFFFFull) q = 0x3FFFFFFFull;
                    slots[(size_t)(base + jb2) * 1024 + r] = (unsigned int)q;
                }
            }
        };

        for (int c = 0; c < 16; ++c) {
            if (c > 0) do_chunk(c - 1);
            __syncthreads();
        }
        do_chunk(15);
    }
}

// ---------------- red: exact per-t reduction of 1024 row probs ----------
__global__ __launch_bounds__(256) void red_k(float* __restrict__ ws)
{
    int tid = threadIdx.x, w = tid >> 6, l = tid & 63;
    int t = 3 + blockIdx.x * 4 + w;
    if (t > 255) return;
    const unsigned int* slots = (const unsigned int*)(ws + OFF_SLOTS);
    unsigned long long* acc = (unsigned long long*)(ws + OFF_ACC);
    unsigned long long s = 0;
    #pragma unroll
    for (int k = 0; k < 16; ++k) s += slots[(size_t)t * 1024 + k * 64 + l];
    #pragma unroll
    for (int o = 32; o; o >>= 1) s += __shfl_xor(s, o);
    if (l == 0) acc[t] = s;
}

// ---------------- fin: inline verdict; no-op on no-fire; replay on fire ----
__global__ __launch_bounds__(256, 1) void fin_k(
    const int* __restrict__ seq, const float* __restrict__ memory,
    const float* __restrict__ gwih, const float* __restrict__ gwhh,
    const float* __restrict__ gbhh, const float* __restrict__ qw,
    const float* __restrict__ qb, const float* __restrict__ kw,
    const float* __restrict__ vw, const float* __restrict__ vb,
    const float* __restrict__ lwih, const float* __restrict__ lwhh,
    const float* __restrict__ lbih, const float* __restrict__ lbhh,
    const float* __restrict__ tw, const float* __restrict__ tb,
    const float* __restrict__ hw, const float* __restrict__ hb,
    float* __restrict__ ws, float* __restrict__ out)
{
    int tid = threadIdx.x, w = tid >> 6, l = tid & 63, b = blockIdx.x;
    const unsigned long long* acc = (const unsigned long long*)(ws + OFF_ACC);

    __shared__ int redmin[4];
    {
        int mymin = 1 << 30;
        if (tid >= 3 && acc[tid] > THRESH30) mymin = tid;
        #pragma unroll
        for (int o = 32; o; o >>= 1) mymin = min(mymin, __shfl_xor(mymin, o));
        if (l == 0) redmin[w] = mymin;
    }
    __syncthreads();
    int tc = min(min(redmin[0], redmin[1]), min(redmin[2], redmin[3]));
    if (tc > 255) {
        if (b == 0 && tid == 0) out[65536] = 0.f;
        return;                         // common path
    }

    int r = b * 4 + w;
    const float* tokproj = ws + OFF_TOKPROJ;
    unsigned int* S2 = (unsigned int*)(ws + OFF_SLOT2);

    __shared__ float hs[4][64], qs[4][64], us[4][64], rs[4][64];
    __shared__ float hs2f[4][32];
    __shared__ float PXl[4][4][128];
    __shared__ unsigned int probq[4];
    __shared__ int flagLds;
    __shared__ int toks[4][256];

    for (int k = 0; k < 4; ++k) toks[w][k * 64 + l] = seq[r * 256 + k * 64 + l];
    if (tid == 0) flagLds = 0;

    float wh0[64], wh1[64], wh2[64], wl0[64], wl1[64], lh0[32], lh1[32];
    #pragma unroll
    for (int d4 = 0; d4 < 16; ++d4) {
        float4 a0 = *(const float4*)(gwhh + (size_t)l * 64 + d4 * 4);
        float4 a1 = *(const float4*)(gwhh + (size_t)(64 + l) * 64 + d4 * 4);
        float4 a2 = *(const float4*)(gwhh + (size_t)(128 + l) * 64 + d4 * 4);
        float4 b0 = *(const float4*)(lwih + (size_t)l * 64 + d4 * 4);
        float4 b1 = *(const float4*)(lwih + (size_t)(64 + l) * 64 + d4 * 4);
        wh0[d4*4] = a0.x; wh0[d4*4+1] = a0.y; wh0[d4*4+2] = a0.z; wh0[d4*4+3] = a0.w;
        wh1[d4*4] = a1.x; wh1[d4*4+1] = a1.y; wh1[d4*4+2] = a1.z; wh1[d4*4+3] = a1.w;
        wh2[d4*4] = a2.x; wh2[d4*4+1] = a2.y; wh2[d4*4+2] = a2.z; wh2[d4*4+3] = a2.w;
        wl0[d4*4] = b0.x; wl0[d4*4+1] = b0.y; wl0[d4*4+2] = b0.z; wl0[d4*4+3] = b0.w;
        wl1[d4*4] = b1.x; wl1[d4*4+1] = b1.y; wl1[d4*4+2] = b1.z; wl1[d4*4+3] = b1.w;
    }
    #pragma unroll
    for (int d4 = 0; d4 < 8; ++d4) {
        float4 c0 = *(const float4*)(lwhh + (size_t)l * 32 + d4 * 4);
        float4 c1 = *(const float4*)(lwhh + (size_t)(64 + l) * 32 + d4 * 4);
        lh0[d4*4] = c0.x; lh0[d4*4+1] = c0.y; lh0[d4*4+2] = c0.z; lh0[d4*4+3] = c0.w;
        lh1[d4*4] = c1.x; lh1[d4*4+1] = c1.y; lh1[d4*4+2] = c1.z; lh1[d4*4+3] = c1.w;
    }
    float g0b = gbhh[l], g1b = gbhh[64 + l], g2b = gbhh[128 + l];
    float lb0 = lbih[l] + lbhh[l], lb1 = lbih[64 + l] + lbhh[64 + l];
    float twr = (l < 32) ? tw[l] : 0.f;
    float tb0 = tb[0];
    const float* mrow = memory + (size_t)r * 16384;

    float h = 0.f;
    hs[w][l] = 0.f;
    bool fire = false, brk = false;
    int cnt = 1;
    __syncthreads();

    for (int t = 0; t < 256; ++t) {
        int tok = toks[w][t];
        float gi0 = tokproj[tok * 192 + l], gi1 = tokproj[tok * 192 + 64 + l],
              gi2 = tokproj[tok * 192 + 128 + l];
        float gh0 = g0b, gh1 = g1b, gh2 = g2b;
        #pragma unroll
        for (int d4 = 0; d4 < 16; ++d4) {
            float4 hv = *(const float4*)&hs[w][d4 * 4];
            gh0 += hv.x*wh0[d4*4] + hv.y*wh0[d4*4+1] + hv.z*wh0[d4*4+2] + hv.w*wh0[d4*4+3];
            gh1 += hv.x*wh1[d4*4] + hv.y*wh1[d4*4+1] + hv.z*wh1[d4*4+2] + hv.w*wh1[d4*4+3];
            gh2 += hv.x*wh2[d4*4] + hv.y*wh2[d4*4+1] + hv.z*wh2[d4*4+2] + hv.w*wh2[d4*4+3];
        }
        if (fire) {
            float q = qb[l];
            #pragma unroll
            for (int d4 = 0; d4 < 16; ++d4) {
                float4 q4 = *(const float4*)(qw + (size_t)l * 64 + d4 * 4);
                float4 hv = *(const float4*)&hs[w][d4 * 4];
                q += hv.x * q4.x + hv.y * q4.y + hv.z * q4.z + hv.w * q4.w;
            }
            qs[w][l] = q;
            float qk = 0.f;
            for (int e = 0; e < 64; ++e) qk += qs[w][e] * kw[(size_t)e * 64 + l];
            qk *= 0.125f;
            us[w][l] = qk;
            float sc[4];
            for (int k = 0; k < 4; ++k) {
                const float* mp = mrow + (size_t)(k * 64 + l) * 64;
                float s = 0.f;
                #pragma unroll
                for (int d4 = 0; d4 < 16; ++d4) {
                    float4 m4 = *(const float4*)(mp + d4 * 4);
                    float4 kv = *(const float4*)&us[w][d4 * 4];
                    s += m4.x * kv.x + m4.y * kv.y + m4.z * kv.z + m4.w * kv.w;
                }
                sc[k] = s;
            }
            float mx = fmaxf(fmaxf(sc[0], sc[1]), fmaxf(sc[2], sc[3]));
            for (int o = 32; o; o >>= 1) mx = fmaxf(mx, __shfl_xor(mx, o));
            float den = 0.f;
            #pragma unroll
            for (int k = 0; k < 4; ++k) { sc[k] = expf(sc[k] - mx); den += sc[k]; }
            for (int o = 32; o; o >>= 1) den += __shfl_xor(den, o);
            float u = 0.f;
            for (int m = 0; m < 256; ++m) {
                float wm = __shfl(sc[m >> 6], m & 63);
                u += wm * mrow[(size_t)m * 64 + l];
            }
            u /= den;
            us[w][l] = u;
            float ret = vb[l];
            #pragma unroll
            for (int d4 = 0; d4 < 16; ++d4) {
                float4 v4 = *(const float4*)(vw + (size_t)l * 64 + d4 * 4);
                float4 uv = *(const float4*)&us[w][d4 * 4];
                ret += uv.x * v4.x + uv.y * v4.y + uv.z * v4.z + uv.w * v4.w;
            }
            rs[w][l] = ret;
            for (int e = 0; e < 64; ++e) {
                float re = rs[w][e];
                gi0 += re * gwih[(size_t)l * 128 + 64 + e];
                gi1 += re * gwih[(size_t)(64 + l) * 128 + 64 + e];
                gi2 += re * gwih[(size_t)(128 + l) * 128 + 64 + e];
            }
        }
        fire = false;
        float r_ = sigf(gi0 + gh0), z_ = sigf(gi1 + gh1);
        float n_ = tanhf_fast(gi2 + r_ * gh2);
        h = (1.f - z_) * n_ + z_ * h;
        hs[w][l] = h;

        float p0 = lb0, p1 = lb1;
        #pragma unroll
        for (int d4 = 0; d4 < 16; ++d4) {
            float4 hv = *(const float4*)&hs[w][d4 * 4];
            p0 += hv.x*wl0[d4*4] + hv.y*wl0[d4*4+1] + hv.z*wl0[d4*4+2] + hv.w*wl0[d4*4+3];
            p1 += hv.x*wl1[d4*4] + hv.y*wl1[d4*4+1] + hv.z*wl1[d4*4+2] + hv.w*wl1[d4*4+3];
        }
        PXl[w][t & 3][l] = p0; PXl[w][t & 3][64 + l] = p1;

        if (t == tc) {
            fire = true;
        } else if (t > tc) {
            float hh = 0.f, cc = 0.f;
            #pragma unroll
            for (int k = 0; k < 4; ++k) {
                int s2 = (t - 3 + k) & 3;
                float q0 = PXl[w][s2][l], q1 = PXl[w][s2][64 + l];
                if (k) {
                    #pragma unroll
                    for (int d4 = 0; d4 < 8; ++d4) {
                        float4 hv = *(const float4*)&hs2f[w][d4 * 4];
                        q0 += hv.x*lh0[d4*4] + hv.y*lh0[d4*4+1] + hv.z*lh0[d4*4+2] + hv.w*lh0[d4*4+3];
                        q1 += hv.x*lh1[d4*4] + hv.y*lh1[d4*4+1] + hv.z*lh1[d4*4+2] + hv.w*lh1[d4*4+3];
                    }
                }
                float f_ = __shfl(q0, l + 32), o_ = __shfl(q1, l + 32);
                float ig = sigf(q0), ff = sigf(f_), gg = tanhf_fast(q1), oo = sigf(o_);
                float ncc = ff * cc + ig * gg;
                float nhh = oo * tanhf_fast(ncc);
                if (l < 32) { cc = ncc; hh = nhh; hs2f[w][l] = nhh; }
            }
            float pp = (l < 32) ? hh * twr : 0.f;
            #pragma unroll
            for (int o = 32; o; o >>= 1) pp += __shfl_xor(pp, o);
            if (l == 0) {
                float prob = sigf(pp + tb0);
                unsigned long long q = (unsigned long long)llrint((double)prob * 134217728.0);
                if (q > 0x7FFFFFFull) q = 0x7FFFFFFull;
                probq[w] = (unsigned int)q;
            }
            __syncthreads();
            if (w == 0 && l == 0) {
                unsigned int s = probq[0] + probq[1] + probq[2] + probq[3];
                __hip_atomic_store(&S2[(size_t)t * 256 + b], (1u << 30) | s,
                                   __ATOMIC_RELAXED, __HIP_MEMORY_SCOPE_AGENT);
            }
            if (w == 0) {
                unsigned long long tot = 0; int spin = 0; bool ok = true;
                if (!brk) {
                    for (;;) {
                        bool all4 = true; tot = 0;
                        #pragma unroll
                        for (int k2 = 0; k2 < 4; ++k2) {
                            unsigned int v = __hip_atomic_load(&S2[(size_t)t * 256 + k2 * 64 + l],
                                                               __ATOMIC_RELAXED, __HIP_MEMORY_SCOPE_AGENT);
                            all4 &= ((v >> 30) == 1u);
                            tot += (v & 0x3FFFFFFFu);
                        }
                        if (__all(all4)) break;
                        if (++spin > SPIN_BOUND) { ok = false; brk = true; break; }
                        __builtin_amdgcn_s_sleep(1);
                    }
                } else ok = false;
                #pragma unroll
                for (int o = 32; o; o >>= 1) tot += __shfl_xor(tot, o);
                int dec = (ok && tot > THRESH27) ? 1 : 0;
                cnt += dec;
                if (l == 0) flagLds = dec;
            }
            __syncthreads();
            fire = (flagLds != 0);
        }
    }

    float sL = hb[l];
    #pragma unroll
    for (int d4 = 0; d4 < 16; ++d4) {
        float4 w4 = *(const float4*)(hw + (size_t)l * 64 + d4 * 4);
        float4 hv = *(const float4*)&hs[w][d4 * 4];
        sL += hv.x * w4.x + hv.y * w4.y + hv.z * w4.z + hv.w * w4.w;
    }
    out[r * 64 + l] = sL;
    if (b == 0 && w == 0 && l == 0)
        out[65536] = brk ? -1234.f : (float)cnt / 256.f;
}

extern "C" void kernel_launch(void* const* d_in, const int* in_sizes, int n_in,
                              void* d_out, int out_size, void* d_ws, size_t ws_size,
                              hipStream_t stream)
{
    const int*   seq    = (const int*)d_in[0];
    const float* memory = (const float*)d_in[1];
    const float* embed  = (const float*)d_in[2];
    const float* gwih   = (const float*)d_in[3];
    const float* gwhh   = (const float*)d_in[4];
    const float* gbih   = (const float*)d_in[5];
    const float* gbhh   = (const float*)d_in[6];
    const float* qw     = (const float*)d_in[7];
    const float* qb     = (const float*)d_in[8];
    const float* kw     = (const float*)d_in[9];
    // d_in[10] = k_b : cancels in softmax, unused
    const float* vw     = (const float*)d_in[11];
    const float* vb     = (const float*)d_in[12];
    const float* lwih   = (const float*)d_in[13];
    const float* lwhh   = (const float*)d_in[14];
    const float* lbih   = (const float*)d_in[15];
    const float* lbhh   = (const float*)d_in[16];
    const float* tw     = (const float*)d_in[17];
    const float* tb     = (const float*)d_in[18];
    const float* hw     = (const float*)d_in[19];
    const float* hb     = (const float*)d_in[20];
    float* ws = (float*)d_ws;
    float* out = (float*)d_out;

    prep_k<<<80, 64, 0, stream>>>(embed, gwih, gbih, ws);
    fused_k<<<256, 512, 0, stream>>>(seq, gwhh, gbhh, lwih, lwhh, lbih, lbhh,
                                     tw, tb, hw, hb, ws, out);
    red_k<<<64, 256, 0, stream>>>(ws);
    fin_k<<<256, 256, 0, stream>>>(seq, memory, gwih, gwhh, gbhh, qw, qb, kw,
                                   vw, vb, lwih, lwhh, lbih, lbhh, tw, tb,
                                   hw, hb, ws, out);
}

// Round 19
// 456.642 us; speedup vs baseline: 2.3379x; 1.1152x over previous
//
#include <hip/hip_runtime.h>
#include <hip/hip_fp16.h>
#include <math.h>

// ws float offsets
#define OFF_TOKPROJ 0         // 12288 floats
#define OFF_ACC     12288     // 256 u64 = 512 floats
#define OFF_SLOT2   12800     // 256*256 u32 (rare path)
#define OFF_SLOTS   78336     // 256*1024 u32 (per-(t,row) q30 probs)

#define THRESH30 (512ULL << 30)
#define THRESH27 (512ULL << 27)
#define SPIN_BOUND (1 << 18)

__device__ __forceinline__ float sigf(float x) {
    return __fdividef(1.f, 1.f + __expf(-x));
}
__device__ __forceinline__ float tanhf_fast(float x) {
    float e2 = __expf(-2.f * fabsf(x));
    float r = __fdividef(1.f - e2, 1.f + e2);
    return __uint_as_float(__float_as_uint(r) | (__float_as_uint(x) & 0x80000000u));
}
// lanes<32: tanh(q) [g-gate]; lanes>=32: sigmoid(q) [o-gate] — one exp+rcp
__device__ __forceinline__ float merged_go(float q, int l) {
    bool lo = (l < 32);
    float e = __expf(lo ? -2.f * fabsf(q) : -q);
    float m = __fdividef(lo ? (1.f - e) : 1.f, 1.f + e);
    if (lo) m = __uint_as_float(__float_as_uint(m) | (__float_as_uint(q) & 0x80000000u));
    return m;
}
__device__ __forceinline__ unsigned int pack2(float x, float y) {
    union { unsigned int u; _Float16 h[2]; } v;
    v.h[0] = (_Float16)x; v.h[1] = (_Float16)y;
    return v.u;
}
__device__ __forceinline__ float unplo(unsigned int u) {
    union { unsigned int x; _Float16 h[2]; } v; v.x = u; return (float)v.h[0];
}
__device__ __forceinline__ float unphi(unsigned int u) {
    union { unsigned int x; _Float16 h[2]; } v; v.x = u; return (float)v.h[1];
}
__device__ __forceinline__ float dot2acc(unsigned int a, unsigned int b, float acc) {
#if __has_builtin(__builtin_amdgcn_fdot2)
    typedef _Float16 hf2 __attribute__((ext_vector_type(2)));
    union { unsigned int u; hf2 h; } ua, ub;
    ua.u = a; ub.u = b;
    return __builtin_amdgcn_fdot2(ua.h, ub.h, acc, false);
#else
    union { unsigned int u; _Float16 h[2]; } ua, ub;
    ua.u = a; ub.u = b;
    return acc + (float)ua.h[0] * (float)ub.h[0] + (float)ua.h[1] * (float)ub.h[1];
#endif
}

// ---------------- prep: tokproj table + zero SLOT2 ----------------
__global__ __launch_bounds__(64) void prep_k(
    const float* __restrict__ embed, const float* __restrict__ gwih,
    const float* __restrict__ gbih, float* __restrict__ ws)
{
    int blk = blockIdx.x, l = threadIdx.x;
    if (blk < 64) {
        float* tokproj = ws + OFF_TOKPROJ;
        int v = blk;
        for (int j = l; j < 192; j += 64) {
            float s = gbih[j];
            for (int d = 0; d < 64; ++d) s += embed[v * 64 + d] * gwih[j * 128 + d];
            tokproj[v * 192 + j] = s;
        }
    } else {
        float* z = ws + OFF_SLOT2;
        int base = (blk - 64) * 4096;
        for (int i = base + l; i < base + 4096; i += 64) z[i] = 0.f;
    }
}

// --- fused: per row, 1 GRU producer wave + 3 trigger consumer waves --------
__global__ __launch_bounds__(256) void fused_k(
    const int* __restrict__ seq, const float* __restrict__ gwhh,
    const float* __restrict__ gbhh, const float* __restrict__ lwih,
    const float* __restrict__ lwhh, const float* __restrict__ lbih,
    const float* __restrict__ lbhh, const float* __restrict__ tw,
    const float* __restrict__ tb, const float* __restrict__ hw,
    const float* __restrict__ hb, float* __restrict__ ws,
    float* __restrict__ out)
{
    int tid = threadIdx.x, w = tid >> 6, l = tid & 63;
    int r = blockIdx.x;
    int gw = r & 3;                       // producer wave, rotated across SIMDs
    const float* tokproj = ws + OFF_TOKPROJ;
    unsigned int* slots = (unsigned int*)(ws + OFF_SLOTS);

    __shared__ unsigned int hbuf[2][19][32];   // packed fp16 h window
    __shared__ unsigned int hs2w[4][16];       // per-wave packed LSTM hidden
    __shared__ int toks[256];

    for (int i = tid; i < 256; i += 256) toks[i] = seq[(size_t)r * 256 + i];
    __syncthreads();

    if (w == gw) {
        // ================= GRU producer =================
        unsigned int wh0h[32], wh1h[32], wh2h[32];
        #pragma unroll
        for (int d2 = 0; d2 < 32; ++d2) {
            wh0h[d2] = pack2(gwhh[(size_t)l * 64 + 2*d2], gwhh[(size_t)l * 64 + 2*d2 + 1]);
            wh1h[d2] = pack2(gwhh[(size_t)(64 + l) * 64 + 2*d2], gwhh[(size_t)(64 + l) * 64 + 2*d2 + 1]);
            wh2h[d2] = pack2(gwhh[(size_t)(128 + l) * 64 + 2*d2], gwhh[(size_t)(128 + l) * 64 + 2*d2 + 1]);
        }
        float g0b = gbhh[l], g1b = gbhh[64 + l], g2b = gbhh[128 + l];
        float h = 0.f;
        if (l < 32) { hbuf[0][0][l] = 0u; hbuf[0][1][l] = 0u; hbuf[0][2][l] = 0u; }
        int tok0 = toks[0];
        float gi0 = tokproj[tok0 * 192 + l], gi1 = tokproj[tok0 * 192 + 64 + l],
              gi2 = tokproj[tok0 * 192 + 128 + l];

        for (int c = 0; c < 16; ++c) {
            int cb = c & 1;
            if (c > 0 && l < 32) {
                hbuf[cb][0][l] = hbuf[cb ^ 1][16][l];
                hbuf[cb][1][l] = hbuf[cb ^ 1][17][l];
                hbuf[cb][2][l] = hbuf[cb ^ 1][18][l];
            }
            for (int s = 0; s < 16; ++s) {
                int t = c * 16 + s;
                float ni0 = 0.f, ni1 = 0.f, ni2 = 0.f;
                if (t < 255) {
                    int tk = toks[t + 1];
                    ni0 = tokproj[tk * 192 + l];
                    ni1 = tokproj[tk * 192 + 64 + l];
                    ni2 = tokproj[tk * 192 + 128 + l];
                }
                float A00 = 0.f, A01 = 0.f, A10 = 0.f, A11 = 0.f, A20 = 0.f, A21 = 0.f;
                #pragma unroll
                for (int d8 = 0; d8 < 8; ++d8) {
                    uint4 hv = *(const uint4*)&hbuf[cb][s + 2][d8 * 4];
                    A00 = dot2acc(hv.x, wh0h[d8*4+0], A00); A01 = dot2acc(hv.y, wh0h[d8*4+1], A01);
                    A00 = dot2acc(hv.z, wh0h[d8*4+2], A00); A01 = dot2acc(hv.w, wh0h[d8*4+3], A01);
                    A10 = dot2acc(hv.x, wh1h[d8*4+0], A10); A11 = dot2acc(hv.y, wh1h[d8*4+1], A11);
                    A10 = dot2acc(hv.z, wh1h[d8*4+2], A10); A11 = dot2acc(hv.w, wh1h[d8*4+3], A11);
                    A20 = dot2acc(hv.x, wh2h[d8*4+0], A20); A21 = dot2acc(hv.y, wh2h[d8*4+1], A21);
                    A20 = dot2acc(hv.z, wh2h[d8*4+2], A20); A21 = dot2acc(hv.w, wh2h[d8*4+3], A21);
                }
                float gh0 = g0b + A00 + A01;
                float gh1 = g1b + A10 + A11;
                float gh2 = g2b + A20 + A21;
                float r_ = sigf(gi0 + gh0), z_ = sigf(gi1 + gh1);
                float n_ = tanhf_fast(gi2 + r_ * gh2);
                h = (1.f - z_) * n_ + z_ * h;
                float a0 = __shfl(h, 2 * l), a1 = __shfl(h, 2 * l + 1);
                if (l < 32) hbuf[cb][s + 3][l] = pack2(a0, a1);
                gi0 = ni0; gi1 = ni1; gi2 = ni2;
            }
            __syncthreads();
        }
        // logits from h_255 (hbuf[1][18], packed)
        float sL = hb[l];
        #pragma unroll
        for (int d4 = 0; d4 < 16; ++d4) {
            float4 w4 = *(const float4*)(hw + (size_t)l * 64 + d4 * 4);
            unsigned int h0 = hbuf[1][18][d4 * 2], h1 = hbuf[1][18][d4 * 2 + 1];
            sL += unplo(h0) * w4.x + unphi(h0) * w4.y + unplo(h1) * w4.z + unphi(h1) * w4.w;
        }
        out[r * 64 + l] = sL;
    } else {
        // ================= trigger consumers (split range 3 ways) ==========
        int tr = (w - gw + 3) & 3;        // 0,1,2
        unsigned int wl0h[32], wl1h[32], lh0h[16], lh1h[16];
        #pragma unroll
        for (int d2 = 0; d2 < 32; ++d2) {
            wl0h[d2] = pack2(lwih[(size_t)l * 64 + 2*d2], lwih[(size_t)l * 64 + 2*d2 + 1]);
            wl1h[d2] = pack2(lwih[(size_t)(64 + l) * 64 + 2*d2], lwih[(size_t)(64 + l) * 64 + 2*d2 + 1]);
        }
        #pragma unroll
        for (int d2 = 0; d2 < 16; ++d2) {
            lh0h[d2] = pack2(lwhh[(size_t)l * 32 + 2*d2], lwhh[(size_t)l * 32 + 2*d2 + 1]);
            lh1h[d2] = pack2(lwhh[(size_t)(64 + l) * 32 + 2*d2], lwhh[(size_t)(64 + l) * 32 + 2*d2 + 1]);
        }
        float lb0 = lbih[l] + lbhh[l], lb1 = lbih[64 + l] + lbhh[64 + l];
        float twr = (l < 32) ? tw[l] : 0.f;
        float tb0 = tb[0];

        auto do_chunk = [&](int cc) {
            int bb = cc & 1, base = cc * 16;
            int tlo = (cc == 0) ? 3 : base;
            int n = base + 16 - tlo;
            int ta = tlo + (tr * n) / 3;
            int tb_ = tlo + ((tr + 1) * n) / 3;
            auto proj = [&](int tt) -> unsigned int {
                int idx = tt - base + 3;
                float p0 = lb0, p1 = lb1;
                #pragma unroll
                for (int d8 = 0; d8 < 8; ++d8) {
                    uint4 hv = *(const uint4*)&hbuf[bb][idx][d8 * 4];
                    p0 = dot2acc(hv.x, wl0h[d8*4+0], p0); p1 = dot2acc(hv.x, wl1h[d8*4+0], p1);
                    p0 = dot2acc(hv.y, wl0h[d8*4+1], p0); p1 = dot2acc(hv.y, wl1h[d8*4+1], p1);
                    p0 = dot2acc(hv.z, wl0h[d8*4+2], p0); p1 = dot2acc(hv.z, wl1h[d8*4+2], p1);
                    p0 = dot2acc(hv.w, wl0h[d8*4+3], p0); p1 = dot2acc(hv.w, wl1h[d8*4+3], p1);
                }
                return pack2(p0, p1);
            };
            unsigned int PW[4];
            for (int t = ta; t < tb_; ++t) {
                if (t == ta) {
                    PW[0] = proj(t - 3); PW[1] = proj(t - 2);
                    PW[2] = proj(t - 1); PW[3] = proj(t);
                } else {
                    PW[0] = PW[1]; PW[1] = PW[2]; PW[2] = PW[3];
                    PW[3] = proj(t);
                }
                float hh = 0.f, cc2 = 0.f;
                #pragma unroll
                for (int k = 0; k < 4; ++k) {
                    float q0 = unplo(PW[k]), q1 = unphi(PW[k]);
                    if (k) {
                        #pragma unroll
                        for (int d4 = 0; d4 < 4; ++d4) {
                            uint4 ha = *(const uint4*)&hs2w[w][d4 * 4];
                            q0 = dot2acc(ha.x, lh0h[d4*4+0], q0); q1 = dot2acc(ha.x, lh1h[d4*4+0], q1);
                            q0 = dot2acc(ha.y, lh0h[d4*4+1], q0); q1 = dot2acc(ha.y, lh1h[d4*4+1], q1);
                            q0 = dot2acc(ha.z, lh0h[d4*4+2], q0); q1 = dot2acc(ha.z, lh1h[d4*4+2], q1);
                            q0 = dot2acc(ha.w, lh0h[d4*4+3], q0); q1 = dot2acc(ha.w, lh1h[d4*4+3], q1);
                        }
                    }
                    float s0 = sigf(q0);              // i (lo), f (hi)
                    float m  = merged_go(q1, l);      // g (lo), o (hi)
                    float ff = __shfl(s0, l + 32);
                    float oo = __shfl(m,  l + 32);
                    float ncc = ff * cc2 + s0 * m;
                    float nh = oo * tanhf_fast(ncc);
                    if (l < 32) { cc2 = ncc; hh = nh; }
                    if (k < 3) {
                        float a0 = __shfl(nh, 2 * l), a1 = __shfl(nh, 2 * l + 1);
                        if (l < 16) hs2w[w][l] = pack2(a0, a1);
                    }
                }
                float pp = (l < 32) ? hh * twr : 0.f;
                #pragma unroll
                for (int o = 32; o; o >>= 1) pp += __shfl_xor(pp, o);
                if (l == 0) {
                    float prob = sigf(pp + tb0);
                    unsigned long long q = (unsigned long long)llrint((double)prob * 1073741824.0);
                    if (q > 0x3FFFFFFFull) q = 0x3FFFFFFFull;
                    slots[(size_t)t * 1024 + r] = (unsigned int)q;
                }
            }
        };

        for (int c = 0; c < 16; ++c) {
            if (c > 0) do_chunk(c - 1);
            __syncthreads();
        }
        do_chunk(15);
    }
}

// ---------------- red: exact per-t reduction of 1024 row probs ----------
__global__ __launch_bounds__(256) void red_k(float* __restrict__ ws)
{
    int tid = threadIdx.x, w = tid >> 6, l = tid & 63;
    int t = 3 + blockIdx.x * 4 + w;
    if (t > 255) return;
    const unsigned int* slots = (const unsigned int*)(ws + OFF_SLOTS);
    unsigned long long* acc = (unsigned long long*)(ws + OFF_ACC);
    unsigned long long s = 0;
    #pragma unroll
    for (int k = 0; k < 16; ++k) s += slots[(size_t)t * 1024 + k * 64 + l];
    #pragma unroll
    for (int o = 32; o; o >>= 1) s += __shfl_xor(s, o);
    if (l == 0) acc[t] = s;
}

// ---------------- fin: inline verdict; no-op on no-fire; replay on fire ----
__global__ __launch_bounds__(256, 1) void fin_k(
    const int* __restrict__ seq, const float* __restrict__ memory,
    const float* __restrict__ gwih, const float* __restrict__ gwhh,
    const float* __restrict__ gbhh, const float* __restrict__ qw,
    const float* __restrict__ qb, const float* __restrict__ kw,
    const float* __restrict__ vw, const float* __restrict__ vb,
    const float* __restrict__ lwih, const float* __restrict__ lwhh,
    const float* __restrict__ lbih, const float* __restrict__ lbhh,
    const float* __restrict__ tw, const float* __restrict__ tb,
    const float* __restrict__ hw, const float* __restrict__ hb,
    float* __restrict__ ws, float* __restrict__ out)
{
    int tid = threadIdx.x, w = tid >> 6, l = tid & 63, b = blockIdx.x;
    const unsigned long long* acc = (const unsigned long long*)(ws + OFF_ACC);

    __shared__ int redmin[4];
    {
        int mymin = 1 << 30;
        if (tid >= 3 && acc[tid] > THRESH30) mymin = tid;
        #pragma unroll
        for (int o = 32; o; o >>= 1) mymin = min(mymin, __shfl_xor(mymin, o));
        if (l == 0) redmin[w] = mymin;
    }
    __syncthreads();
    int tc = min(min(redmin[0], redmin[1]), min(redmin[2], redmin[3]));
    if (tc > 255) {
        if (b == 0 && tid == 0) out[65536] = 0.f;
        return;                         // common path
    }

    int r = b * 4 + w;
    const float* tokproj = ws + OFF_TOKPROJ;
    unsigned int* S2 = (unsigned int*)(ws + OFF_SLOT2);

    __shared__ float hs[4][64], qs[4][64], us[4][64], rs[4][64];
    __shared__ float hs2f[4][32];
    __shared__ float PXl[4][4][128];
    __shared__ unsigned int probq[4];
    __shared__ int flagLds;
    __shared__ int toks[4][256];

    for (int k = 0; k < 4; ++k) toks[w][k * 64 + l] = seq[r * 256 + k * 64 + l];
    if (tid == 0) flagLds = 0;

    float wh0[64], wh1[64], wh2[64], wl0[64], wl1[64], lh0[32], lh1[32];
    #pragma unroll
    for (int d4 = 0; d4 < 16; ++d4) {
        float4 a0 = *(const float4*)(gwhh + (size_t)l * 64 + d4 * 4);
        float4 a1 = *(const float4*)(gwhh + (size_t)(64 + l) * 64 + d4 * 4);
        float4 a2 = *(const float4*)(gwhh + (size_t)(128 + l) * 64 + d4 * 4);
        float4 b0 = *(const float4*)(lwih + (size_t)l * 64 + d4 * 4);
        float4 b1 = *(const float4*)(lwih + (size_t)(64 + l) * 64 + d4 * 4);
        wh0[d4*4] = a0.x; wh0[d4*4+1] = a0.y; wh0[d4*4+2] = a0.z; wh0[d4*4+3] = a0.w;
        wh1[d4*4] = a1.x; wh1[d4*4+1] = a1.y; wh1[d4*4+2] = a1.z; wh1[d4*4+3] = a1.w;
        wh2[d4*4] = a2.x; wh2[d4*4+1] = a2.y; wh2[d4*4+2] = a2.z; wh2[d4*4+3] = a2.w;
        wl0[d4*4] = b0.x; wl0[d4*4+1] = b0.y; wl0[d4*4+2] = b0.z; wl0[d4*4+3] = b0.w;
        wl1[d4*4] = b1.x; wl1[d4*4+1] = b1.y; wl1[d4*4+2] = b1.z; wl1[d4*4+3] = b1.w;
    }
    #pragma unroll
    for (int d4 = 0; d4 < 8; ++d4) {
        float4 c0 = *(const float4*)(lwhh + (size_t)l * 32 + d4 * 4);
        float4 c1 = *(const float4*)(lwhh + (size_t)(64 + l) * 32 + d4 * 4);
        lh0[d4*4] = c0.x; lh0[d4*4+1] = c0.y; lh0[d4*4+2] = c0.z; lh0[d4*4+3] = c0.w;
        lh1[d4*4] = c1.x; lh1[d4*4+1] = c1.y; lh1[d4*4+2] = c1.z; lh1[d4*4+3] = c1.w;
    }
    float g0b = gbhh[l], g1b = gbhh[64 + l], g2b = gbhh[128 + l];
    float lb0 = lbih[l] + lbhh[l], lb1 = lbih[64 + l] + lbhh[64 + l];
    float twr = (l < 32) ? tw[l] : 0.f;
    float tb0 = tb[0];
    const float* mrow = memory + (size_t)r * 16384;

    float h = 0.f;
    hs[w][l] = 0.f;
    bool fire = false, brk = false;
    int cnt = 1;
    __syncthreads();

    for (int t = 0; t < 256; ++t) {
        int tok = toks[w][t];
        float gi0 = tokproj[tok * 192 + l], gi1 = tokproj[tok * 192 + 64 + l],
              gi2 = tokproj[tok * 192 + 128 + l];
        float gh0 = g0b, gh1 = g1b, gh2 = g2b;
        #pragma unroll
        for (int d4 = 0; d4 < 16; ++d4) {
            float4 hv = *(const float4*)&hs[w][d4 * 4];
            gh0 += hv.x*wh0[d4*4] + hv.y*wh0[d4*4+1] + hv.z*wh0[d4*4+2] + hv.w*wh0[d4*4+3];
            gh1 += hv.x*wh1[d4*4] + hv.y*wh1[d4*4+1] + hv.z*wh1[d4*4+2] + hv.w*wh1[d4*4+3];
            gh2 += hv.x*wh2[d4*4] + hv.y*wh2[d4*4+1] + hv.z*wh2[d4*4+2] + hv.w*wh2[d4*4+3];
        }
        if (fire) {
            float q = qb[l];
            #pragma unroll
            for (int d4 = 0; d4 < 16; ++d4) {
                float4 q4 = *(const float4*)(qw + (size_t)l * 64 + d4 * 4);
                float4 hv = *(const float4*)&hs[w][d4 * 4];
                q += hv.x * q4.x + hv.y * q4.y + hv.z * q4.z + hv.w * q4.w;
            }
            qs[w][l] = q;
            float qk = 0.f;
            for (int e = 0; e < 64; ++e) qk += qs[w][e] * kw[(size_t)e * 64 + l];
            qk *= 0.125f;
            us[w][l] = qk;
            float sc[4];
            for (int k = 0; k < 4; ++k) {
                const float* mp = mrow + (size_t)(k * 64 + l) * 64;
                float s = 0.f;
                #pragma unroll
                for (int d4 = 0; d4 < 16; ++d4) {
                    float4 m4 = *(const float4*)(mp + d4 * 4);
                    float4 kv = *(const float4*)&us[w][d4 * 4];
                    s += m4.x * kv.x + m4.y * kv.y + m4.z * kv.z + m4.w * kv.w;
                }
                sc[k] = s;
            }
            float mx = fmaxf(fmaxf(sc[0], sc[1]), fmaxf(sc[2], sc[3]));
            for (int o = 32; o; o >>= 1) mx = fmaxf(mx, __shfl_xor(mx, o));
            float den = 0.f;
            #pragma unroll
            for (int k = 0; k < 4; ++k) { sc[k] = expf(sc[k] - mx); den += sc[k]; }
            for (int o = 32; o; o >>= 1) den += __shfl_xor(den, o);
            float u = 0.f;
            for (int m = 0; m < 256; ++m) {
                float wm = __shfl(sc[m >> 6], m & 63);
                u += wm * mrow[(size_t)m * 64 + l];
            }
            u /= den;
            us[w][l] = u;
            float ret = vb[l];
            #pragma unroll
            for (int d4 = 0; d4 < 16; ++d4) {
                float4 v4 = *(const float4*)(vw + (size_t)l * 64 + d4 * 4);
                float4 uv = *(const float4*)&us[w][d4 * 4];
                ret += uv.x * v4.x + uv.y * v4.y + uv.z * v4.z + uv.w * v4.w;
            }
            rs[w][l] = ret;
            for (int e = 0; e < 64; ++e) {
                float re = rs[w][e];
                gi0 += re * gwih[(size_t)l * 128 + 64 + e];
                gi1 += re * gwih[(size_t)(64 + l) * 128 + 64 + e];
                gi2 += re * gwih[(size_t)(128 + l) * 128 + 64 + e];
            }
        }
        fire = false;
        float r_ = sigf(gi0 + gh0), z_ = sigf(gi1 + gh1);
        float n_ = tanhf_fast(gi2 + r_ * gh2);
        h = (1.f - z_) * n_ + z_ * h;
        hs[w][l] = h;

        float p0 = lb0, p1 = lb1;
        #pragma unroll
        for (int d4 = 0; d4 < 16; ++d4) {
            float4 hv = *(const float4*)&hs[w][d4 * 4];
            p0 += hv.x*wl0[d4*4] + hv.y*wl0[d4*4+1] + hv.z*wl0[d4*4+2] + hv.w*wl0[d4*4+3];
            p1 += hv.x*wl1[d4*4] + hv.y*wl1[d4*4+1] + hv.z*wl1[d4*4+2] + hv.w*wl1[d4*4+3];
        }
        PXl[w][t & 3][l] = p0; PXl[w][t & 3][64 + l] = p1;

        if (t == tc) {
            fire = true;
        } else if (t > tc) {
            float hh = 0.f, cc = 0.f;
            #pragma unroll
            for (int k = 0; k < 4; ++k) {
                int s2 = (t - 3 + k) & 3;
                float q0 = PXl[w][s2][l], q1 = PXl[w][s2][64 + l];
                if (k) {
                    #pragma unroll
                    for (int d4 = 0; d4 < 8; ++d4) {
                        float4 hv = *(const float4*)&hs2f[w][d4 * 4];
                        q0 += hv.x*lh0[d4*4] + hv.y*lh0[d4*4+1] + hv.z*lh0[d4*4+2] + hv.w*lh0[d4*4+3];
                        q1 += hv.x*lh1[d4*4] + hv.y*lh1[d4*4+1] + hv.z*lh1[d4*4+2] + hv.w*lh1[d4*4+3];
                    }
                }
                float f_ = __shfl(q0, l + 32), o_ = __shfl(q1, l + 32);
                float ig = sigf(q0), ff = sigf(f_), gg = tanhf_fast(q1), oo = sigf(o_);
                float ncc = ff * cc + ig * gg;
                float nhh = oo * tanhf_fast(ncc);
                if (l < 32) { cc = ncc; hh = nhh; hs2f[w][l] = nhh; }
            }
            float pp = (l < 32) ? hh * twr : 0.f;
            #pragma unroll
            for (int o = 32; o; o >>= 1) pp += __shfl_xor(pp, o);
            if (l == 0) {
                float prob = sigf(pp + tb0);
                unsigned long long q = (unsigned long long)llrint((double)prob * 134217728.0);
                if (q > 0x7FFFFFFull) q = 0x7FFFFFFull;
                probq[w] = (unsigned int)q;
            }
            __syncthreads();
            if (w == 0 && l == 0) {
                unsigned int s = probq[0] + probq[1] + probq[2] + probq[3];
                __hip_atomic_store(&S2[(size_t)t * 256 + b], (1u << 30) | s,
                                   __ATOMIC_RELAXED, __HIP_MEMORY_SCOPE_AGENT);
            }
            if (w == 0) {
                unsigned long long tot = 0; int spin = 0; bool ok = true;
                if (!brk) {
                    for (;;) {
                        bool all4 = true; tot = 0;
                        #pragma unroll
                        for (int k2 = 0; k2 < 4; ++k2) {
                            unsigned int v = __hip_atomic_load(&S2[(size_t)t * 256 + k2 * 64 + l],
                                                               __ATOMIC_RELAXED, __HIP_MEMORY_SCOPE_AGENT);
                            all4 &= ((v >> 30) == 1u);
                            tot += (v & 0x3FFFFFFFu);
                        }
                        if (__all(all4)) break;
                        if (++spin > SPIN_BOUND) { ok = false; brk = true; break; }
                        __builtin_amdgcn_s_sleep(1);
                    }
                } else ok = false;
                #pragma unroll
                for (int o = 32; o; o >>= 1) tot += __shfl_xor(tot, o);
                int dec = (ok && tot > THRESH27) ? 1 : 0;
                cnt += dec;
                if (l == 0) flagLds = dec;
            }
            __syncthreads();
            fire = (flagLds != 0);
        }
    }

    float sL = hb[l];
    #pragma unroll
    for (int d4 = 0; d4 < 16; ++d4) {
        float4 w4 = *(const float4*)(hw + (size_t)l * 64 + d4 * 4);
        float4 hv = *(const float4*)&hs[w][d4 * 4];
        sL += hv.x * w4.x + hv.y * w4.y + hv.z * w4.z + hv.w * w4.w;
    }
    out[r * 64 + l] = sL;
    if (b == 0 && w == 0 && l == 0)
        out[65536] = brk ? -1234.f : (float)cnt / 256.f;
}

extern "C" void kernel_launch(void* const* d_in, const int* in_sizes, int n_in,
                              void* d_out, int out_size, void* d_ws, size_t ws_size,
                              hipStream_t stream)
{
    const int*   seq    = (const int*)d_in[0];
    const float* memory = (const float*)d_in[1];
    const float* embed  = (const float*)d_in[2];
    const float* gwih   = (const float*)d_in[3];
    const float* gwhh   = (const float*)d_in[4];
    const float* gbih   = (const float*)d_in[5];
    const float* gbhh   = (const float*)d_in[6];
    const float* qw     = (const float*)d_in[7];
    const float* qb     = (const float*)d_in[8];
    const float* kw     = (const float*)d_in[9];
    // d_in[10] = k_b : cancels in softmax, unused
    const float* vw     = (const float*)d_in[11];
    const float* vb     = (const float*)d_in[12];
    const float* lwih   = (const float*)d_in[13];
    const float* lwhh   = (const float*)d_in[14];
    const float* lbih   = (const float*)d_in[15];
    const float* lbhh   = (const float*)d_in[16];
    const float* tw     = (const float*)d_in[17];
    const float* tb     = (const float*)d_in[18];
    const float* hw     = (const float*)d_in[19];
    const float* hb     = (const float*)d_in[20];
    float* ws = (float*)d_ws;
    float* out = (float*)d_out;

    prep_k<<<80, 64, 0, stream>>>(embed, gwih, gbih, ws);
    fused_k<<<1024, 256, 0, stream>>>(seq, gwhh, gbhh, lwih, lwhh, lbih, lbhh,
                                      tw, tb, hw, hb, ws, out);
    red_k<<<64, 256, 0, stream>>>(ws);
    fin_k<<<256, 256, 0, stream>>>(seq, memory, gwih, gwhh, gbhh, qw, qb, kw,
                                   vw, vb, lwih, lwhh, lbih, lbhh, tw, tb,
                                   hw, hb, ws, out);
}

// Round 20
// 441.899 us; speedup vs baseline: 2.4159x; 1.0334x over previous
//
#include <hip/hip_runtime.h>
#include <hip/hip_fp16.h>
#include <math.h>

// ws float offsets
#define OFF_TOKPROJ 0         // 12288 floats
#define OFF_ACC     12288     // 256 u64 = 512 floats
#define OFF_SLOT2   12800     // 256*256 u32 (rare path)
#define OFF_SLOTS   78336     // 256*1024 u32 (per-(t,row) q30 probs)

#define THRESH30 (512ULL << 30)
#define THRESH27 (512ULL << 27)
#define SPIN_BOUND (1 << 18)

__device__ __forceinline__ float sigf(float x) {
    return __fdividef(1.f, 1.f + __expf(-x));
}
__device__ __forceinline__ float tanhf_fast(float x) {
    float e2 = __expf(-2.f * fabsf(x));
    float r = __fdividef(1.f - e2, 1.f + e2);
    return __uint_as_float(__float_as_uint(r) | (__float_as_uint(x) & 0x80000000u));
}
// lanes<32: tanh(q) [g]; lanes>=32: sigmoid(q) [o] — one exp+rcp
__device__ __forceinline__ float merged_go(float q, int l) {
    bool lo = (l < 32);
    float e = __expf(lo ? -2.f * fabsf(q) : -q);
    float m = __fdividef(lo ? (1.f - e) : 1.f, 1.f + e);
    if (lo) m = __uint_as_float(__float_as_uint(m) | (__float_as_uint(q) & 0x80000000u));
    return m;
}
__device__ __forceinline__ unsigned int pack2(float x, float y) {
    union { unsigned int u; _Float16 h[2]; } v;
    v.h[0] = (_Float16)x; v.h[1] = (_Float16)y;
    return v.u;
}
__device__ __forceinline__ float unplo(unsigned int u) {
    union { unsigned int x; _Float16 h[2]; } v; v.x = u; return (float)v.h[0];
}
__device__ __forceinline__ float unphi(unsigned int u) {
    union { unsigned int x; _Float16 h[2]; } v; v.x = u; return (float)v.h[1];
}
__device__ __forceinline__ float dot2acc(unsigned int a, unsigned int b, float acc) {
#if __has_builtin(__builtin_amdgcn_fdot2)
    typedef _Float16 hf2 __attribute__((ext_vector_type(2)));
    union { unsigned int u; hf2 h; } ua, ub;
    ua.u = a; ub.u = b;
    return __builtin_amdgcn_fdot2(ua.h, ub.h, acc, false);
#else
    union { unsigned int u; _Float16 h[2]; } ua, ub;
    ua.u = a; ub.u = b;
    return acc + (float)ua.h[0] * (float)ub.h[0] + (float)ua.h[1] * (float)ub.h[1];
#endif
}

// ---------------- prep: tokproj table + zero SLOT2 ----------------
__global__ __launch_bounds__(64) void prep_k(
    const float* __restrict__ embed, const float* __restrict__ gwih,
    const float* __restrict__ gbih, float* __restrict__ ws)
{
    int blk = blockIdx.x, l = threadIdx.x;
    if (blk < 64) {
        float* tokproj = ws + OFF_TOKPROJ;
        int v = blk;
        for (int j = l; j < 192; j += 64) {
            float s = gbih[j];
            for (int d = 0; d < 64; ++d) s += embed[v * 64 + d] * gwih[j * 128 + d];
            tokproj[v * 192 + j] = s;
        }
    } else {
        float* z = ws + OFF_SLOT2;
        int base = (blk - 64) * 4096;
        for (int i = base + l; i < base + 4096; i += 64) z[i] = 0.f;
    }
}

// --- fused: dual-row GRU producer wave + 3 trigger consumer waves ----------
__global__ __launch_bounds__(256) void fused_k(
    const int* __restrict__ seq, const float* __restrict__ gwhh,
    const float* __restrict__ gbhh, const float* __restrict__ lwih,
    const float* __restrict__ lwhh, const float* __restrict__ lbih,
    const float* __restrict__ lbhh, const float* __restrict__ tw,
    const float* __restrict__ tb, const float* __restrict__ hw,
    const float* __restrict__ hb, float* __restrict__ ws,
    float* __restrict__ out)
{
    int tid = threadIdx.x, w = tid >> 6, l = tid & 63;
    int b = blockIdx.x;                   // rows 2b, 2b+1
    int gw = b & 3;                       // producer wave, rotated across SIMDs
    const float* tokproj = ws + OFF_TOKPROJ;
    unsigned int* slots = (unsigned int*)(ws + OFF_SLOTS);

    __shared__ unsigned int hbuf[2][2][19][32];   // [row][buf] packed fp16 h window
    __shared__ unsigned int hs2w[4][16];          // per-wave packed LSTM hidden
    __shared__ int toks[2][256];

    for (int i = tid; i < 512; i += 256) toks[i >> 8][i & 255] = seq[(size_t)b * 512 + i];
    __syncthreads();

    if (w == gw) {
        // ============ GRU producer: two independent chains (ILP) ============
        unsigned int wh0h[32], wh1h[32], wh2h[32];
        #pragma unroll
        for (int d2 = 0; d2 < 32; ++d2) {
            wh0h[d2] = pack2(gwhh[(size_t)l * 64 + 2*d2], gwhh[(size_t)l * 64 + 2*d2 + 1]);
            wh1h[d2] = pack2(gwhh[(size_t)(64 + l) * 64 + 2*d2], gwhh[(size_t)(64 + l) * 64 + 2*d2 + 1]);
            wh2h[d2] = pack2(gwhh[(size_t)(128 + l) * 64 + 2*d2], gwhh[(size_t)(128 + l) * 64 + 2*d2 + 1]);
        }
        float g0b = gbhh[l], g1b = gbhh[64 + l], g2b = gbhh[128 + l];
        float h0 = 0.f, h1 = 0.f;
        if (l < 32) {
            hbuf[0][0][0][l] = 0u; hbuf[0][0][1][l] = 0u; hbuf[0][0][2][l] = 0u;
            hbuf[1][0][0][l] = 0u; hbuf[1][0][1][l] = 0u; hbuf[1][0][2][l] = 0u;
        }
        int ta = toks[0][0], tbk = toks[1][0];
        float ga0 = tokproj[ta * 192 + l], ga1 = tokproj[ta * 192 + 64 + l],
              ga2 = tokproj[ta * 192 + 128 + l];
        float gb0 = tokproj[tbk * 192 + l], gb1 = tokproj[tbk * 192 + 64 + l],
              gb2 = tokproj[tbk * 192 + 128 + l];

        for (int c = 0; c < 16; ++c) {
            int cb = c & 1;
            if (c > 0 && l < 32) {
                hbuf[0][cb][0][l] = hbuf[0][cb ^ 1][16][l];
                hbuf[0][cb][1][l] = hbuf[0][cb ^ 1][17][l];
                hbuf[0][cb][2][l] = hbuf[0][cb ^ 1][18][l];
                hbuf[1][cb][0][l] = hbuf[1][cb ^ 1][16][l];
                hbuf[1][cb][1][l] = hbuf[1][cb ^ 1][17][l];
                hbuf[1][cb][2][l] = hbuf[1][cb ^ 1][18][l];
            }
            for (int s = 0; s < 16; ++s) {
                int t = c * 16 + s;
                float na0 = 0.f, na1 = 0.f, na2 = 0.f, nb0 = 0.f, nb1 = 0.f, nb2 = 0.f;
                if (t < 255) {
                    int tk0 = toks[0][t + 1], tk1 = toks[1][t + 1];
                    na0 = tokproj[tk0 * 192 + l];
                    na1 = tokproj[tk0 * 192 + 64 + l];
                    na2 = tokproj[tk0 * 192 + 128 + l];
                    nb0 = tokproj[tk1 * 192 + l];
                    nb1 = tokproj[tk1 * 192 + 64 + l];
                    nb2 = tokproj[tk1 * 192 + 128 + l];
                }
                float A00=0.f, A01=0.f, A10=0.f, A11=0.f, A20=0.f, A21=0.f;
                float B00=0.f, B01=0.f, B10=0.f, B11=0.f, B20=0.f, B21=0.f;
                #pragma unroll
                for (int d8 = 0; d8 < 8; ++d8) {
                    uint4 hv0 = *(const uint4*)&hbuf[0][cb][s + 2][d8 * 4];
                    uint4 hv1 = *(const uint4*)&hbuf[1][cb][s + 2][d8 * 4];
                    A00 = dot2acc(hv0.x, wh0h[d8*4+0], A00); A01 = dot2acc(hv0.y, wh0h[d8*4+1], A01);
                    B00 = dot2acc(hv1.x, wh0h[d8*4+0], B00); B01 = dot2acc(hv1.y, wh0h[d8*4+1], B01);
                    A00 = dot2acc(hv0.z, wh0h[d8*4+2], A00); A01 = dot2acc(hv0.w, wh0h[d8*4+3], A01);
                    B00 = dot2acc(hv1.z, wh0h[d8*4+2], B00); B01 = dot2acc(hv1.w, wh0h[d8*4+3], B01);
                    A10 = dot2acc(hv0.x, wh1h[d8*4+0], A10); A11 = dot2acc(hv0.y, wh1h[d8*4+1], A11);
                    B10 = dot2acc(hv1.x, wh1h[d8*4+0], B10); B11 = dot2acc(hv1.y, wh1h[d8*4+1], B11);
                    A10 = dot2acc(hv0.z, wh1h[d8*4+2], A10); A11 = dot2acc(hv0.w, wh1h[d8*4+3], A11);
                    B10 = dot2acc(hv1.z, wh1h[d8*4+2], B10); B11 = dot2acc(hv1.w, wh1h[d8*4+3], B11);
                    A20 = dot2acc(hv0.x, wh2h[d8*4+0], A20); A21 = dot2acc(hv0.y, wh2h[d8*4+1], A21);
                    B20 = dot2acc(hv1.x, wh2h[d8*4+0], B20); B21 = dot2acc(hv1.y, wh2h[d8*4+1], B21);
                    A20 = dot2acc(hv0.z, wh2h[d8*4+2], A20); A21 = dot2acc(hv0.w, wh2h[d8*4+3], A21);
                    B20 = dot2acc(hv1.z, wh2h[d8*4+2], B20); B21 = dot2acc(hv1.w, wh2h[d8*4+3], B21);
                }
                float r0_ = sigf(ga0 + g0b + A00 + A01);
                float r1_ = sigf(gb0 + g0b + B00 + B01);
                float z0_ = sigf(ga1 + g1b + A10 + A11);
                float z1_ = sigf(gb1 + g1b + B10 + B11);
                float n0_ = tanhf_fast(ga2 + r0_ * (g2b + A20 + A21));
                float n1_ = tanhf_fast(gb2 + r1_ * (g2b + B20 + B21));
                h0 = (1.f - z0_) * n0_ + z0_ * h0;
                h1 = (1.f - z1_) * n1_ + z1_ * h1;
                float a0 = __shfl(h0, 2 * l), a1 = __shfl(h0, 2 * l + 1);
                float b0 = __shfl(h1, 2 * l), b1 = __shfl(h1, 2 * l + 1);
                if (l < 32) {
                    hbuf[0][cb][s + 3][l] = pack2(a0, a1);
                    hbuf[1][cb][s + 3][l] = pack2(b0, b1);
                }
                ga0 = na0; ga1 = na1; ga2 = na2;
                gb0 = nb0; gb1 = nb1; gb2 = nb2;
            }
            __syncthreads();
        }
        // logits for both rows from packed h_255 (hbuf[row][1][18])
        #pragma unroll
        for (int row = 0; row < 2; ++row) {
            float sL = hb[l];
            #pragma unroll
            for (int d4 = 0; d4 < 16; ++d4) {
                float4 w4 = *(const float4*)(hw + (size_t)l * 64 + d4 * 4);
                unsigned int q0 = hbuf[row][1][18][d4 * 2], q1 = hbuf[row][1][18][d4 * 2 + 1];
                sL += unplo(q0) * w4.x + unphi(q0) * w4.y + unplo(q1) * w4.z + unphi(q1) * w4.w;
            }
            out[(size_t)(b * 2 + row) * 64 + l] = sL;
        }
    } else {
        // ========== trigger consumers: split 2xN items 3 ways ==========
        int tr = (w - gw + 3) & 3;        // 0,1,2
        unsigned int wl0h[32], wl1h[32], lh0h[16], lh1h[16];
        #pragma unroll
        for (int d2 = 0; d2 < 32; ++d2) {
            wl0h[d2] = pack2(lwih[(size_t)l * 64 + 2*d2], lwih[(size_t)l * 64 + 2*d2 + 1]);
            wl1h[d2] = pack2(lwih[(size_t)(64 + l) * 64 + 2*d2], lwih[(size_t)(64 + l) * 64 + 2*d2 + 1]);
        }
        #pragma unroll
        for (int d2 = 0; d2 < 16; ++d2) {
            lh0h[d2] = pack2(lwhh[(size_t)l * 32 + 2*d2], lwhh[(size_t)l * 32 + 2*d2 + 1]);
            lh1h[d2] = pack2(lwhh[(size_t)(64 + l) * 32 + 2*d2], lwhh[(size_t)(64 + l) * 32 + 2*d2 + 1]);
        }
        float lb0 = lbih[l] + lbhh[l], lb1 = lbih[64 + l] + lbhh[64 + l];
        float twr = (l < 32) ? tw[l] : 0.f;
        float tb0 = tb[0];

        auto do_chunk = [&](int cc) {
            int bb = cc & 1, base = cc * 16;
            int tlo = (cc == 0) ? 3 : base;
            int n = base + 16 - tlo;
            int total = 2 * n;
            int i0 = (tr * total) / 3, i1 = ((tr + 1) * total) / 3;
            int i = i0;
            while (i < i1) {
                int row = i / n;
                int tstart = tlo + (i - row * n);
                int iend = min(i1, (row + 1) * n);
                int tend = tlo + (iend - row * n);
                auto proj = [&](int tt) -> unsigned int {
                    int idx = tt - base + 3;
                    float p0 = lb0, p1 = lb1;
                    #pragma unroll
                    for (int d8 = 0; d8 < 8; ++d8) {
                        uint4 hv = *(const uint4*)&hbuf[row][bb][idx][d8 * 4];
                        p0 = dot2acc(hv.x, wl0h[d8*4+0], p0); p1 = dot2acc(hv.x, wl1h[d8*4+0], p1);
                        p0 = dot2acc(hv.y, wl0h[d8*4+1], p0); p1 = dot2acc(hv.y, wl1h[d8*4+1], p1);
                        p0 = dot2acc(hv.z, wl0h[d8*4+2], p0); p1 = dot2acc(hv.z, wl1h[d8*4+2], p1);
                        p0 = dot2acc(hv.w, wl0h[d8*4+3], p0); p1 = dot2acc(hv.w, wl1h[d8*4+3], p1);
                    }
                    return pack2(p0, p1);
                };
                unsigned int PW[4];
                PW[0] = proj(tstart - 3); PW[1] = proj(tstart - 2);
                PW[2] = proj(tstart - 1); PW[3] = proj(tstart);
                for (int t = tstart; t < tend; ++t) {
                    if (t > tstart) {
                        PW[0] = PW[1]; PW[1] = PW[2]; PW[2] = PW[3];
                        PW[3] = proj(t);
                    }
                    float hh = 0.f, cc2 = 0.f;
                    #pragma unroll
                    for (int k = 0; k < 4; ++k) {
                        float q0 = unplo(PW[k]), q1 = unphi(PW[k]);
                        if (k) {
                            #pragma unroll
                            for (int d4 = 0; d4 < 4; ++d4) {
                                uint4 ha = *(const uint4*)&hs2w[w][d4 * 4];
                                q0 = dot2acc(ha.x, lh0h[d4*4+0], q0); q1 = dot2acc(ha.x, lh1h[d4*4+0], q1);
                                q0 = dot2acc(ha.y, lh0h[d4*4+1], q0); q1 = dot2acc(ha.y, lh1h[d4*4+1], q1);
                                q0 = dot2acc(ha.z, lh0h[d4*4+2], q0); q1 = dot2acc(ha.z, lh1h[d4*4+2], q1);
                                q0 = dot2acc(ha.w, lh0h[d4*4+3], q0); q1 = dot2acc(ha.w, lh1h[d4*4+3], q1);
                            }
                        }
                        float s0 = sigf(q0);              // i (lo), f (hi)
                        float m  = merged_go(q1, l);      // g (lo), o (hi)
                        float ff = __shfl(s0, l + 32);
                        float oo = __shfl(m,  l + 32);
                        float ncc = ff * cc2 + s0 * m;
                        float nh = oo * tanhf_fast(ncc);
                        if (l < 32) { cc2 = ncc; hh = nh; }
                        if (k < 3) {
                            float a0 = __shfl(nh, 2 * l), a1 = __shfl(nh, 2 * l + 1);
                            if (l < 16) hs2w[w][l] = pack2(a0, a1);
                        }
                    }
                    float pp = (l < 32) ? hh * twr : 0.f;
                    #pragma unroll
                    for (int o = 32; o; o >>= 1) pp += __shfl_xor(pp, o);
                    if (l == 0) {
                        float prob = sigf(pp + tb0);
                        unsigned long long q = (unsigned long long)llrint((double)prob * 1073741824.0);
                        if (q > 0x3FFFFFFFull) q = 0x3FFFFFFFull;
                        slots[(size_t)t * 1024 + (b * 2 + row)] = (unsigned int)q;
                    }
                }
                i = iend;
            }
        };

        for (int c = 0; c < 16; ++c) {
            if (c > 0) do_chunk(c - 1);
            __syncthreads();
        }
        do_chunk(15);
    }
}

// ---------------- red: exact per-t reduction of 1024 row probs ----------
__global__ __launch_bounds__(256) void red_k(float* __restrict__ ws)
{
    int tid = threadIdx.x, w = tid >> 6, l = tid & 63;
    int t = 3 + blockIdx.x * 4 + w;
    if (t > 255) return;
    const unsigned int* slots = (const unsigned int*)(ws + OFF_SLOTS);
    unsigned long long* acc = (unsigned long long*)(ws + OFF_ACC);
    unsigned long long s = 0;
    #pragma unroll
    for (int k = 0; k < 16; ++k) s += slots[(size_t)t * 1024 + k * 64 + l];
    #pragma unroll
    for (int o = 32; o; o >>= 1) s += __shfl_xor(s, o);
    if (l == 0) acc[t] = s;
}

// ---------------- fin: inline verdict; no-op on no-fire; replay on fire ----
__global__ __launch_bounds__(256, 1) void fin_k(
    const int* __restrict__ seq, const float* __restrict__ memory,
    const float* __restrict__ gwih, const float* __restrict__ gwhh,
    const float* __restrict__ gbhh, const float* __restrict__ qw,
    const float* __restrict__ qb, const float* __restrict__ kw,
    const float* __restrict__ vw, const float* __restrict__ vb,
    const float* __restrict__ lwih, const float* __restrict__ lwhh,
    const float* __restrict__ lbih, const float* __restrict__ lbhh,
    const float* __restrict__ tw, const float* __restrict__ tb,
    const float* __restrict__ hw, const float* __restrict__ hb,
    float* __restrict__ ws, float* __restrict__ out)
{
    int tid = threadIdx.x, w = tid >> 6, l = tid & 63, b = blockIdx.x;
    const unsigned long long* acc = (const unsigned long long*)(ws + OFF_ACC);

    __shared__ int redmin[4];
    {
        int mymin = 1 << 30;
        if (tid >= 3 && acc[tid] > THRESH30) mymin = tid;
        #pragma unroll
        for (int o = 32; o; o >>= 1) mymin = min(mymin, __shfl_xor(mymin, o));
        if (l == 0) redmin[w] = mymin;
    }
    __syncthreads();
    int tc = min(min(redmin[0], redmin[1]), min(redmin[2], redmin[3]));
    if (tc > 255) {
        if (b == 0 && tid == 0) out[65536] = 0.f;
        return;                         // common path
    }

    int r = b * 4 + w;
    const float* tokproj = ws + OFF_TOKPROJ;
    unsigned int* S2 = (unsigned int*)(ws + OFF_SLOT2);

    __shared__ float hs[4][64], qs[4][64], us[4][64], rs[4][64];
    __shared__ float hs2f[4][32];
    __shared__ float PXl[4][4][128];
    __shared__ unsigned int probq[4];
    __shared__ int flagLds;
    __shared__ int toks[4][256];

    for (int k = 0; k < 4; ++k) toks[w][k * 64 + l] = seq[r * 256 + k * 64 + l];
    if (tid == 0) flagLds = 0;

    float wh0[64], wh1[64], wh2[64], wl0[64], wl1[64], lh0[32], lh1[32];
    #pragma unroll
    for (int d4 = 0; d4 < 16; ++d4) {
        float4 a0 = *(const float4*)(gwhh + (size_t)l * 64 + d4 * 4);
        float4 a1 = *(const float4*)(gwhh + (size_t)(64 + l) * 64 + d4 * 4);
        float4 a2 = *(const float4*)(gwhh + (size_t)(128 + l) * 64 + d4 * 4);
        float4 b0 = *(const float4*)(lwih + (size_t)l * 64 + d4 * 4);
        float4 b1 = *(const float4*)(lwih + (size_t)(64 + l) * 64 + d4 * 4);
        wh0[d4*4] = a0.x; wh0[d4*4+1] = a0.y; wh0[d4*4+2] = a0.z; wh0[d4*4+3] = a0.w;
        wh1[d4*4] = a1.x; wh1[d4*4+1] = a1.y; wh1[d4*4+2] = a1.z; wh1[d4*4+3] = a1.w;
        wh2[d4*4] = a2.x; wh2[d4*4+1] = a2.y; wh2[d4*4+2] = a2.z; wh2[d4*4+3] = a2.w;
        wl0[d4*4] = b0.x; wl0[d4*4+1] = b0.y; wl0[d4*4+2] = b0.z; wl0[d4*4+3] = b0.w;
        wl1[d4*4] = b1.x; wl1[d4*4+1] = b1.y; wl1[d4*4+2] = b1.z; wl1[d4*4+3] = b1.w;
    }
    #pragma unroll
    for (int d4 = 0; d4 < 8; ++d4) {
        float4 c0 = *(const float4*)(lwhh + (size_t)l * 32 + d4 * 4);
        float4 c1 = *(const float4*)(lwhh + (size_t)(64 + l) * 32 + d4 * 4);
        lh0[d4*4] = c0.x; lh0[d4*4+1] = c0.y; lh0[d4*4+2] = c0.z; lh0[d4*4+3] = c0.w;
        lh1[d4*4] = c1.x; lh1[d4*4+1] = c1.y; lh1[d4*4+2] = c1.z; lh1[d4*4+3] = c1.w;
    }
    float g0b = gbhh[l], g1b = gbhh[64 + l], g2b = gbhh[128 + l];
    float lb0 = lbih[l] + lbhh[l], lb1 = lbih[64 + l] + lbhh[64 + l];
    float twr = (l < 32) ? tw[l] : 0.f;
    float tb0 = tb[0];
    const float* mrow = memory + (size_t)r * 16384;

    float h = 0.f;
    hs[w][l] = 0.f;
    bool fire = false, brk = false;
    int cnt = 1;
    __syncthreads();

    for (int t = 0; t < 256; ++t) {
        int tok = toks[w][t];
        float gi0 = tokproj[tok * 192 + l], gi1 = tokproj[tok * 192 + 64 + l],
              gi2 = tokproj[tok * 192 + 128 + l];
        float gh0 = g0b, gh1 = g1b, gh2 = g2b;
        #pragma unroll
        for (int d4 = 0; d4 < 16; ++d4) {
            float4 hv = *(const float4*)&hs[w][d4 * 4];
            gh0 += hv.x*wh0[d4*4] + hv.y*wh0[d4*4+1] + hv.z*wh0[d4*4+2] + hv.w*wh0[d4*4+3];
            gh1 += hv.x*wh1[d4*4] + hv.y*wh1[d4*4+1] + hv.z*wh1[d4*4+2] + hv.w*wh1[d4*4+3];
            gh2 += hv.x*wh2[d4*4] + hv.y*wh2[d4*4+1] + hv.z*wh2[d4*4+2] + hv.w*wh2[d4*4+3];
        }
        if (fire) {
            float q = qb[l];
            #pragma unroll
            for (int d4 = 0; d4 < 16; ++d4) {
                float4 q4 = *(const float4*)(qw + (size_t)l * 64 + d4 * 4);
                float4 hv = *(const float4*)&hs[w][d4 * 4];
                q += hv.x * q4.x + hv.y * q4.y + hv.z * q4.z + hv.w * q4.w;
            }
            qs[w][l] = q;
            float qk = 0.f;
            for (int e = 0; e < 64; ++e) qk += qs[w][e] * kw[(size_t)e * 64 + l];
            qk *= 0.125f;
            us[w][l] = qk;
            float sc[4];
            for (int k = 0; k < 4; ++k) {
                const float* mp = mrow + (size_t)(k * 64 + l) * 64;
                float s = 0.f;
                #pragma unroll
                for (int d4 = 0; d4 < 16; ++d4) {
                    float4 m4 = *(const float4*)(mp + d4 * 4);
                    float4 kv = *(const float4*)&us[w][d4 * 4];
                    s += m4.x * kv.x + m4.y * kv.y + m4.z * kv.z + m4.w * kv.w;
                }
                sc[k] = s;
            }
            float mx = fmaxf(fmaxf(sc[0], sc[1]), fmaxf(sc[2], sc[3]));
            for (int o = 32; o; o >>= 1) mx = fmaxf(mx, __shfl_xor(mx, o));
            float den = 0.f;
            #pragma unroll
            for (int k = 0; k < 4; ++k) { sc[k] = expf(sc[k] - mx); den += sc[k]; }
            for (int o = 32; o; o >>= 1) den += __shfl_xor(den, o);
            float u = 0.f;
            for (int m = 0; m < 256; ++m) {
                float wm = __shfl(sc[m >> 6], m & 63);
                u += wm * mrow[(size_t)m * 64 + l];
            }
            u /= den;
            us[w][l] = u;
            float ret = vb[l];
            #pragma unroll
            for (int d4 = 0; d4 < 16; ++d4) {
                float4 v4 = *(const float4*)(vw + (size_t)l * 64 + d4 * 4);
                float4 uv = *(const float4*)&us[w][d4 * 4];
                ret += uv.x * v4.x + uv.y * v4.y + uv.z * v4.z + uv.w * v4.w;
            }
            rs[w][l] = ret;
            for (int e = 0; e < 64; ++e) {
                float re = rs[w][e];
                gi0 += re * gwih[(size_t)l * 128 + 64 + e];
                gi1 += re * gwih[(size_t)(64 + l) * 128 + 64 + e];
                gi2 += re * gwih[(size_t)(128 + l) * 128 + 64 + e];
            }
        }
        fire = false;
        float r_ = sigf(gi0 + gh0), z_ = sigf(gi1 + gh1);
        float n_ = tanhf_fast(gi2 + r_ * gh2);
        h = (1.f - z_) * n_ + z_ * h;
        hs[w][l] = h;

        float p0 = lb0, p1 = lb1;
        #pragma unroll
        for (int d4 = 0; d4 < 16; ++d4) {
            float4 hv = *(const float4*)&hs[w][d4 * 4];
            p0 += hv.x*wl0[d4*4] + hv.y*wl0[d4*4+1] + hv.z*wl0[d4*4+2] + hv.w*wl0[d4*4+3];
            p1 += hv.x*wl1[d4*4] + hv.y*wl1[d4*4+1] + hv.z*wl1[d4*4+2] + hv.w*wl1[d4*4+3];
        }
        PXl[w][t & 3][l] = p0; PXl[w][t & 3][64 + l] = p1;

        if (t == tc) {
            fire = true;
        } else if (t > tc) {
            float hh = 0.f, cc = 0.f;
            #pragma unroll
            for (int k = 0; k < 4; ++k) {
                int s2 = (t - 3 + k) & 3;
                float q0 = PXl[w][s2][l], q1 = PXl[w][s2][64 + l];
                if (k) {
                    #pragma unroll
                    for (int d4 = 0; d4 < 8; ++d4) {
                        float4 hv = *(const float4*)&hs2f[w][d4 * 4];
                        q0 += hv.x*lh0[d4*4] + hv.y*lh0[d4*4+1] + hv.z*lh0[d4*4+2] + hv.w*lh0[d4*4+3];
                        q1 += hv.x*lh1[d4*4] + hv.y*lh1[d4*4+1] + hv.z*lh1[d4*4+2] + hv.w*lh1[d4*4+3];
                    }
                }
                float f_ = __shfl(q0, l + 32), o_ = __shfl(q1, l + 32);
                float ig = sigf(q0), ff = sigf(f_), gg = tanhf_fast(q1), oo = sigf(o_);
                float ncc = ff * cc + ig * gg;
                float nhh = oo * tanhf_fast(ncc);
                if (l < 32) { cc = ncc; hh = nhh; hs2f[w][l] = nhh; }
            }
            float pp = (l < 32) ? hh * twr : 0.f;
            #pragma unroll
            for (int o = 32; o; o >>= 1) pp += __shfl_xor(pp, o);
            if (l == 0) {
                float prob = sigf(pp + tb0);
                unsigned long long q = (unsigned long long)llrint((double)prob * 134217728.0);
                if (q > 0x7FFFFFFull) q = 0x7FFFFFFull;
                probq[w] = (unsigned int)q;
            }
            __syncthreads();
            if (w == 0 && l == 0) {
                unsigned int s = probq[0] + probq[1] + probq[2] + probq[3];
                __hip_atomic_store(&S2[(size_t)t * 256 + b], (1u << 30) | s,
                                   __ATOMIC_RELAXED, __HIP_MEMORY_SCOPE_AGENT);
            }
            if (w == 0) {
                unsigned long long tot = 0; int spin = 0; bool ok = true;
                if (!brk) {
                    for (;;) {
                        bool all4 = true; tot = 0;
                        #pragma unroll
                        for (int k2 = 0; k2 < 4; ++k2) {
                            unsigned int v = __hip_atomic_load(&S2[(size_t)t * 256 + k2 * 64 + l],
                                                               __ATOMIC_RELAXED, __HIP_MEMORY_SCOPE_AGENT);
                            all4 &= ((v >> 30) == 1u);
                            tot += (v & 0x3FFFFFFFu);
                        }
                        if (__all(all4)) break;
                        if (++spin > SPIN_BOUND) { ok = false; brk = true; break; }
                        __builtin_amdgcn_s_sleep(1);
                    }
                } else ok = false;
                #pragma unroll
                for (int o = 32; o; o >>= 1) tot += __shfl_xor(tot, o);
                int dec = (ok && tot > THRESH27) ? 1 : 0;
                cnt += dec;
                if (l == 0) flagLds = dec;
            }
            __syncthreads();
            fire = (flagLds != 0);
        }
    }

    float sL = hb[l];
    #pragma unroll
    for (int d4 = 0; d4 < 16; ++d4) {
        float4 w4 = *(const float4*)(hw + (size_t)l * 64 + d4 * 4);
        float4 hv = *(const float4*)&hs[w][d4 * 4];
        sL += hv.x * w4.x + hv.y * w4.y + hv.z * w4.z + hv.w * w4.w;
    }
    out[r * 64 + l] = sL;
    if (b == 0 && w == 0 && l == 0)
        out[65536] = brk ? -1234.f : (float)cnt / 256.f;
}

extern "C" void kernel_launch(void* const* d_in, const int* in_sizes, int n_in,
                              void* d_out, int out_size, void* d_ws, size_t ws_size,
                              hipStream_t stream)
{
    const int*   seq    = (const int*)d_in[0];
    const float* memory = (const float*)d_in[1];
    const float* embed  = (const float*)d_in[2];
    const float* gwih   = (const float*)d_in[3];
    const float* gwhh   = (const float*)d_in[4];
    const float* gbih   = (const float*)d_in[5];
    const float* gbhh   = (const float*)d_in[6];
    const float* qw     = (const float*)d_in[7];
    const float* qb     = (const float*)d_in[8];
    const float* kw     = (const float*)d_in[9];
    // d_in[10] = k_b : cancels in softmax, unused
    const float* vw     = (const float*)d_in[11];
    const float* vb     = (const float*)d_in[12];
    const float* lwih   = (const float*)d_in[13];
    const float* lwhh   = (const float*)d_in[14];
    const float* lbih   = (const float*)d_in[15];
    const float* lbhh   = (const float*)d_in[16];
    const float* tw     = (const float*)d_in[17];
    const float* tb     = (const float*)d_in[18];
    const float* hw     = (const float*)d_in[19];
    const float* hb     = (const float*)d_in[20];
    float* ws = (float*)d_ws;
    float* out = (float*)d_out;

    prep_k<<<80, 64, 0, stream>>>(embed, gwih, gbih, ws);
    fused_k<<<512, 256, 0, stream>>>(seq, gwhh, gbhh, lwih, lwhh, lbih, lbhh,
                                     tw, tb, hw, hb, ws, out);
    red_k<<<64, 256, 0, stream>>>(ws);
    fin_k<<<256, 256, 0, stream>>>(seq, memory, gwih, gwhh, gbhh, qw, qb, kw,
                                   vw, vb, lwih, lwhh, lbih, lbhh, tw, tb,
                                   hw, hb, ws, out);
}